// Round 11
// baseline (2082.340 us; speedup 1.0000x reference)
//
#include <hip/hip_runtime.h>
#include <cstdint>

#define T_ 4
#define B_ 16
#define N_ 256
#define C_ 512
#define H_ 8
#define HID_ 2048
#define M_ (T_*B_*N_)      // 16384 rows
#define BNP_ (B_*N_)       // 4096 (b,n) pairs

// ---------------------------------------------------------------------------
// f32 GEMM v3 — BIT-IDENTICAL per-element math to R1 (single accumulator,
// ascending-k fmaf chain, plain +bias). Retiled: BM=BN=64, BK=16, 256 thr,
// 4x4 micro-tile (~50 VGPR, no spill), double-buffered LDS + reg prefetch.
// Grid 2048+ blocks -> 8 blocks/CU -> full 32-wave occupancy.
// ---------------------------------------------------------------------------
__global__ __launch_bounds__(256)
void gemm_f32_t64(const float* __restrict__ A, const float* __restrict__ W,
                  const float* __restrict__ bias, float* __restrict__ Y,
                  int Nc, int K) {
  __shared__ float As[2][16][68];   // [buf][k][row], padded
  __shared__ float Ws[2][16][68];   // [buf][k][col], padded
  const int tid  = threadIdx.x;
  const int row0 = blockIdx.y * 64;
  const int col0 = blockIdx.x * 64;
  const int tx = tid & 15, ty = tid >> 4;   // micro-tile coords
  const int lr = tid >> 2;                  // 0..63 staging row
  const int lk = (tid & 3) << 2;            // 0,4,8,12 staging k-offset

  float acc[4][4];
  #pragma unroll
  for (int i = 0; i < 4; ++i)
    #pragma unroll
    for (int j = 0; j < 4; ++j) acc[i][j] = 0.f;

  const float* Ap = A + (size_t)(row0 + lr) * K + lk;
  const float* Wp = W + (size_t)(col0 + lr) * K + lk;

  float4 pa = *(const float4*)Ap;
  float4 pw = *(const float4*)Wp;
  As[0][lk+0][lr] = pa.x; As[0][lk+1][lr] = pa.y;
  As[0][lk+2][lr] = pa.z; As[0][lk+3][lr] = pa.w;
  Ws[0][lk+0][lr] = pw.x; Ws[0][lk+1][lr] = pw.y;
  Ws[0][lk+2][lr] = pw.z; Ws[0][lk+3][lr] = pw.w;
  __syncthreads();

  int buf = 0;
  for (int k0 = 0; k0 < K; k0 += 16) {
    const bool last = (k0 + 16 >= K);
    if (!last) {                        // issue next-tile loads early
      pa = *(const float4*)(Ap + k0 + 16);
      pw = *(const float4*)(Wp + k0 + 16);
    }
    #pragma unroll
    for (int kk = 0; kk < 16; ++kk) {   // ascending k — exact chain order
      float4 av = *(const float4*)&As[buf][kk][ty*4];
      float4 bv = *(const float4*)&Ws[buf][kk][tx*4];
      acc[0][0] = fmaf(av.x, bv.x, acc[0][0]);
      acc[0][1] = fmaf(av.x, bv.y, acc[0][1]);
      acc[0][2] = fmaf(av.x, bv.z, acc[0][2]);
      acc[0][3] = fmaf(av.x, bv.w, acc[0][3]);
      acc[1][0] = fmaf(av.y, bv.x, acc[1][0]);
      acc[1][1] = fmaf(av.y, bv.y, acc[1][1]);
      acc[1][2] = fmaf(av.y, bv.z, acc[1][2]);
      acc[1][3] = fmaf(av.y, bv.w, acc[1][3]);
      acc[2][0] = fmaf(av.z, bv.x, acc[2][0]);
      acc[2][1] = fmaf(av.z, bv.y, acc[2][1]);
      acc[2][2] = fmaf(av.z, bv.z, acc[2][2]);
      acc[2][3] = fmaf(av.z, bv.w, acc[2][3]);
      acc[3][0] = fmaf(av.w, bv.x, acc[3][0]);
      acc[3][1] = fmaf(av.w, bv.y, acc[3][1]);
      acc[3][2] = fmaf(av.w, bv.z, acc[3][2]);
      acc[3][3] = fmaf(av.w, bv.w, acc[3][3]);
    }
    if (!last) {
      int nb = buf ^ 1;
      As[nb][lk+0][lr] = pa.x; As[nb][lk+1][lr] = pa.y;
      As[nb][lk+2][lr] = pa.z; As[nb][lk+3][lr] = pa.w;
      Ws[nb][lk+0][lr] = pw.x; Ws[nb][lk+1][lr] = pw.y;
      Ws[nb][lk+2][lr] = pw.z; Ws[nb][lk+3][lr] = pw.w;
      __syncthreads();
      buf = nb;
    }
  }

  #pragma unroll
  for (int i = 0; i < 4; ++i) {
    size_t r = (size_t)(row0 + ty*4 + i);
    int c = col0 + tx*4;
    float4 o4;
    o4.x = acc[i][0] + bias[c+0];       // same plain add as R1
    o4.y = acc[i][1] + bias[c+1];
    o4.z = acc[i][2] + bias[c+2];
    o4.w = acc[i][3] + bias[c+3];
    *(float4*)(Y + r * Nc + c) = o4;
  }
}

// ---------------------------------------------------------------------------
// v/p path GEMM (R9-verbatim): f32 in/out, f64 accumulation.
// ---------------------------------------------------------------------------
__global__ __launch_bounds__(256)
void gemm_nt_f64acc(const float* __restrict__ A, const float* __restrict__ W,
                    const float* __restrict__ bias, float* __restrict__ Y,
                    int Nc, int K) {
  __shared__ float As[16][68];   // [k][row], padded
  __shared__ float Ws[16][68];   // [k][col], padded
  const int tid  = threadIdx.x;
  const int row0 = blockIdx.y * 64;
  const int col0 = blockIdx.x * 64;
  const int tx = tid & 15, ty = tid >> 4;

  double acc[4][4];
  #pragma unroll
  for (int i = 0; i < 4; ++i)
    #pragma unroll
    for (int j = 0; j < 4; ++j) acc[i][j] = 0.0;

  const int lr = tid >> 2;         // 0..63
  const int lk = (tid & 3) << 2;   // 0,4,8,12

  for (int k0 = 0; k0 < K; k0 += 16) {
    __syncthreads();
    {
      float4 a4 = *(const float4*)(A + (size_t)(row0 + lr) * K + (k0 + lk));
      As[lk+0][lr] = a4.x; As[lk+1][lr] = a4.y; As[lk+2][lr] = a4.z; As[lk+3][lr] = a4.w;
      float4 w4 = *(const float4*)(W + (size_t)(col0 + lr) * K + (k0 + lk));
      Ws[lk+0][lr] = w4.x; Ws[lk+1][lr] = w4.y; Ws[lk+2][lr] = w4.z; Ws[lk+3][lr] = w4.w;
    }
    __syncthreads();
    #pragma unroll
    for (int kk = 0; kk < 16; ++kk) {
      double a[4], b[4];
      #pragma unroll
      for (int i = 0; i < 4; ++i) a[i] = (double)As[kk][ty*4+i];
      #pragma unroll
      for (int j = 0; j < 4; ++j) b[j] = (double)Ws[kk][tx*4+j];
      #pragma unroll
      for (int i = 0; i < 4; ++i)
        #pragma unroll
        for (int j = 0; j < 4; ++j)
          acc[i][j] = fma(a[i], b[j], acc[i][j]);
    }
  }
  #pragma unroll
  for (int i = 0; i < 4; ++i) {
    size_t r = (size_t)(row0 + ty*4 + i);
    int c = col0 + tx*4;
    float4 o4;
    o4.x = (float)(acc[i][0] + (double)bias[c+0]);
    o4.y = (float)(acc[i][1] + (double)bias[c+1]);
    o4.z = (float)(acc[i][2] + (double)bias[c+2]);
    o4.w = (float)(acc[i][3] + (double)bias[c+3]);
    *(float4*)(Y + r * Nc + c) = o4;
  }
}

// ---------------------------------------------------------------------------
// BN stats stage 1 (R1-verbatim)
// ---------------------------------------------------------------------------
__global__ __launch_bounds__(256)
void col_stats_partial(const float* __restrict__ Y, int Nc,
                       float* __restrict__ psum, float* __restrict__ psq) {
  const int r0 = blockIdx.x * 32;
  for (int c = threadIdx.x; c < Nc; c += 256) {
    float s = 0.f, q = 0.f;
    const float* p = Y + (size_t)r0 * Nc + c;
    for (int r = 0; r < 32; ++r) {
      float v = p[(size_t)r * Nc];
      s += v;
      q = fmaf(v, v, q);
    }
    psum[(size_t)blockIdx.x * Nc + c] = s;
    psq [(size_t)blockIdx.x * Nc + c] = q;
  }
}

// stage 2 (R1-verbatim): f32 chp for q/k/f1/f2 paths
__global__ void col_stats_final(const float* __restrict__ psum, const float* __restrict__ psq,
                                int Nc, const float* __restrict__ g, const float* __restrict__ beta,
                                float* __restrict__ chp) {
  int c = blockIdx.x * blockDim.x + threadIdx.x;
  if (c >= Nc) return;
  double s = 0.0, q = 0.0;
  for (int p = 0; p < 512; ++p) {
    s += (double)psum[(size_t)p * Nc + c];
    q += (double)psq [(size_t)p * Nc + c];
  }
  double mean = s / (double)M_;
  double var  = q / (double)M_ - mean * mean;
  float alpha = g[c] / sqrtf((float)var + 1e-5f);
  chp[2*c]   = alpha;
  chp[2*c+1] = fmaf(-(float)mean, alpha, beta[c]);   // beta - mean*alpha
}

// stage 2 for v/p paths: f64 affine params (R9-verbatim)
__global__ void col_stats_final_f64(const float* __restrict__ psum, const float* __restrict__ psq,
                                    int Nc, const float* __restrict__ g, const float* __restrict__ beta,
                                    double* __restrict__ chpd) {
  int c = blockIdx.x * blockDim.x + threadIdx.x;
  if (c >= Nc) return;
  double s = 0.0, q = 0.0;
  for (int p = 0; p < 512; ++p) {
    s += (double)psum[(size_t)p * Nc + c];
    q += (double)psq [(size_t)p * Nc + c];
  }
  double mean = s / (double)M_;
  double var  = q / (double)M_ - mean * mean;
  double alpha = (double)g[c] / sqrt(var + 1e-5);
  chpd[2*c]   = alpha;
  chpd[2*c+1] = (double)beta[c] - mean * alpha;
}

// ---------------------------------------------------------------------------
// BN + LIF masks (R1-verbatim) — q/k decisions, frozen
// ---------------------------------------------------------------------------
__global__ __launch_bounds__(256)
void bnlif_mask(const float* __restrict__ Y, const float* __restrict__ chp,
                unsigned long long* __restrict__ mask) {
  int lane = threadIdx.x & 63;
  int u  = blockIdx.x * 4 + (threadIdx.x >> 6);
  int bn = u >> 3, cg = u & 7;          // cg == head (Dh==64)
  int c  = cg * 64 + lane;
  float alpha = chp[2*c], bb = chp[2*c+1];
  float v = 0.f;
  #pragma unroll
  for (int t = 0; t < 4; ++t) {
    float y  = Y[((size_t)(t * BNP_ + bn)) * C_ + c];
    float uu = fmaf(y, alpha, bb);
    v = v + (uu - v) * 0.5f;            // v += (x - v)/tau, tau=2
    bool sp = (v >= 1.0f);
    unsigned long long m = __ballot(sp);
    if (sp) v = 0.f;                    // hard reset
    if (lane == 0) mask[((size_t)(t * BNP_ + bn)) * H_ + cg] = m;
  }
}

// BN apply (v path), f64 math → f32 out (R9-verbatim)
__global__ void bn_apply_f64(const float* __restrict__ Y, const double* __restrict__ chpd,
                             float* __restrict__ out) {
  const long total4 = (long)M_ * C_ / 4;
  for (long i = (long)blockIdx.x * blockDim.x + threadIdx.x; i < total4;
       i += (long)gridDim.x * blockDim.x) {
    int c4 = (int)(i & (C_/4 - 1)) * 4;
    float4 y = ((const float4*)Y)[i];
    float4 r;
    r.x = (float)fma((double)y.x, chpd[2*(c4+0)], chpd[2*(c4+0)+1]);
    r.y = (float)fma((double)y.y, chpd[2*(c4+1)], chpd[2*(c4+1)+1]);
    r.z = (float)fma((double)y.z, chpd[2*(c4+2)], chpd[2*(c4+2)+1]);
    r.w = (float)fma((double)y.w, chpd[2*(c4+3)], chpd[2*(c4+3)+1]);
    ((float4*)out)[i] = r;
  }
}

// xo = x + BN(Yp), f64 math → f32 out (R9-verbatim)
__global__ void bn_residual_f64(const float* __restrict__ Y, const double* __restrict__ chpd,
                                const float* __restrict__ x, float* __restrict__ out) {
  const long total4 = (long)M_ * C_ / 4;
  for (long i = (long)blockIdx.x * blockDim.x + threadIdx.x; i < total4;
       i += (long)gridDim.x * blockDim.x) {
    int c4 = (int)(i & (C_/4 - 1)) * 4;
    float4 y = ((const float4*)Y)[i];
    float4 xv = ((const float4*)x)[i];
    float4 r;
    r.x = (float)((double)xv.x + fma((double)y.x, chpd[2*(c4+0)], chpd[2*(c4+0)+1]));
    r.y = (float)((double)xv.y + fma((double)y.y, chpd[2*(c4+1)], chpd[2*(c4+1)+1]));
    r.z = (float)((double)xv.z + fma((double)y.z, chpd[2*(c4+2)], chpd[2*(c4+2)+1]));
    r.w = (float)((double)xv.w + fma((double)y.w, chpd[2*(c4+3)], chpd[2*(c4+3)+1]));
    ((float4*)out)[i] = r;
  }
}

// BN + LIF for f1 (R1-verbatim), spikes in place as 1.0f/0.0f
__global__ __launch_bounds__(256)
void bnlif_inplace(float* __restrict__ Y, const float* __restrict__ chp) {
  int c  = blockIdx.x * 256 + threadIdx.x;   // < 2048
  int bn = blockIdx.y;
  float alpha = chp[2*c], bb = chp[2*c+1];
  float v = 0.f;
  #pragma unroll
  for (int t = 0; t < 4; ++t) {
    size_t idx = ((size_t)(t * BNP_ + bn)) * HID_ + c;
    float uu = fmaf(Y[idx], alpha, bb);
    v = v + (uu - v) * 0.5f;
    bool sp = (v >= 1.f);
    Y[idx] = sp ? 1.f : 0.f;
    if (sp) v = 0.f;
  }
}

// BN + LIF for f2 + final residual (R1-verbatim)
__global__ __launch_bounds__(256)
void bnlif_final(const float* __restrict__ Y, const float* __restrict__ chp,
                 const float* __restrict__ xo, float* __restrict__ out) {
  int c  = blockIdx.x * 256 + threadIdx.x;   // < 512
  int bn = blockIdx.y;
  float alpha = chp[2*c], bb = chp[2*c+1];
  float v = 0.f;
  #pragma unroll
  for (int t = 0; t < 4; ++t) {
    size_t idx = ((size_t)(t * BNP_ + bn)) * C_ + c;
    float uu = fmaf(Y[idx], alpha, bb);
    v = v + (uu - v) * 0.5f;
    bool sp = (v >= 1.f);
    out[idx] = xo[idx] + (sp ? 1.f : 0.f);
    if (sp) v = 0.f;
  }
}

// ---------------------------------------------------------------------------
// Attention (R9-verbatim): popcount QK (exact); PV accumulated in f64.
// ---------------------------------------------------------------------------
__global__ __launch_bounds__(256)
void attn_kernel_f64(const unsigned long long* __restrict__ qmask,
                     const unsigned long long* __restrict__ kmask,
                     const float* __restrict__ v, float* __restrict__ o) {
  __shared__ unsigned long long km[256];
  __shared__ float vt[256][64];
  int rb  = blockIdx.x & 3;
  int tbh = blockIdx.x >> 2;
  int h   = tbh & 7, tb = tbh >> 3;     // tb = t*16+b
  int tid = threadIdx.x;

  km[tid] = kmask[(size_t)(tb * 256 + tid) * H_ + h];
  const float* vbase = v + (size_t)tb * 256 * C_ + h * 64;
  #pragma unroll
  for (int i = 0; i < 16; ++i) {
    int f = i * 256 + tid;
    int r = f >> 4, c4 = f & 15;
    *(float4*)&vt[r][c4 * 4] = *(const float4*)(vbase + (size_t)r * C_ + c4 * 4);
  }
  int lane = tid & 63, w = tid >> 6;
  int nr = lane & 15, dg = lane >> 4;
  int n  = rb * 64 + w * 16 + nr;
  unsigned long long qm = qmask[(size_t)(tb * 256 + n) * H_ + h];
  __syncthreads();

  double acc[16];
  #pragma unroll
  for (int j = 0; j < 16; ++j) acc[j] = 0.0;

  for (int m = 0; m < 256; ++m) {
    double s = (double)__popcll(qm & km[m]) * 0.125;   // exact
    #pragma unroll
    for (int j = 0; j < 4; ++j) {
      float4 vv = *(const float4*)&vt[m][dg * 16 + j * 4];
      acc[j*4+0] = fma(s, (double)vv.x, acc[j*4+0]);
      acc[j*4+1] = fma(s, (double)vv.y, acc[j*4+1]);
      acc[j*4+2] = fma(s, (double)vv.z, acc[j*4+2]);
      acc[j*4+3] = fma(s, (double)vv.w, acc[j*4+3]);
    }
  }
  float* orow = o + (size_t)(tb * 256 + n) * C_ + h * 64 + dg * 16;
  #pragma unroll
  for (int j = 0; j < 4; ++j)
    *(float4*)(orow + j * 4) = make_float4((float)acc[j*4], (float)acc[j*4+1],
                                           (float)acc[j*4+2], (float)acc[j*4+3]);
}

// ---------------------------------------------------------------------------
extern "C" void kernel_launch(void* const* d_in, const int* in_sizes, int n_in,
                              void* d_out, int out_size, void* d_ws, size_t ws_size,
                              hipStream_t stream) {
  const float* x    = (const float*)d_in[0];
  const float* qw   = (const float*)d_in[2];
  const float* qb   = (const float*)d_in[3];
  const float* qg   = (const float*)d_in[4];
  const float* qbe  = (const float*)d_in[5];
  const float* kw   = (const float*)d_in[6];
  const float* kb   = (const float*)d_in[7];
  const float* kg   = (const float*)d_in[8];
  const float* kbe  = (const float*)d_in[9];
  const float* vw   = (const float*)d_in[10];
  const float* vb   = (const float*)d_in[11];
  const float* vg   = (const float*)d_in[12];
  const float* vbe  = (const float*)d_in[13];
  const float* pw   = (const float*)d_in[14];
  const float* pb   = (const float*)d_in[15];
  const float* pg   = (const float*)d_in[16];
  const float* pbe  = (const float*)d_in[17];
  const float* f1w  = (const float*)d_in[18];
  const float* f1b  = (const float*)d_in[19];
  const float* f1g  = (const float*)d_in[20];
  const float* f1be = (const float*)d_in[21];
  const float* f2w  = (const float*)d_in[22];
  const float* f2b  = (const float*)d_in[23];
  const float* f2g  = (const float*)d_in[24];
  const float* f2be = (const float*)d_in[25];

  char* ws = (char*)d_ws;
  float* bufY = (float*)(ws);                                   // 128 MB (16384x2048 f32)
  float* bufV = (float*)(ws + 134217728ull);                    //  32 MB
  float* bufO = (float*)(ws + 167772160ull);                    //  32 MB (o, then xo)
  unsigned long long* qmask = (unsigned long long*)(ws + 201326592ull);  // 1 MB
  unsigned long long* kmask = (unsigned long long*)(ws + 202375168ull);  // 1 MB
  float* psum = (float*)(ws + 203423744ull);                    // 4 MB (512 x 2048)
  float* psq  = (float*)(ws + 207618048ull);                    // 4 MB
  float* chp  = (float*)(ws + 211812352ull);                    // 16 KB
  double* chpd = (double*)(ws + 211828736ull);                  // 8 KB

  float* out = (float*)d_out;

  // ---- q path (bit-identical values, 64x64 retile) ----
  gemm_f32_t64<<<dim3(8,256), 256, 0, stream>>>(x, qw, qb, bufY, C_, C_);
  col_stats_partial<<<512, 256, 0, stream>>>(bufY, C_, psum, psq);
  col_stats_final<<<2, 256, 0, stream>>>(psum, psq, C_, qg, qbe, chp);
  bnlif_mask<<<8192, 256, 0, stream>>>(bufY, chp, qmask);
  // ---- k path ----
  gemm_f32_t64<<<dim3(8,256), 256, 0, stream>>>(x, kw, kb, bufY, C_, C_);
  col_stats_partial<<<512, 256, 0, stream>>>(bufY, C_, psum, psq);
  col_stats_final<<<2, 256, 0, stream>>>(psum, psq, C_, kg, kbe, chp);
  bnlif_mask<<<8192, 256, 0, stream>>>(bufY, chp, kmask);
  // ---- v path (R9-verbatim: f64-internal) ----
  gemm_nt_f64acc<<<dim3(8,256), 256, 0, stream>>>(x, vw, vb, bufY, C_, C_);
  col_stats_partial<<<512, 256, 0, stream>>>(bufY, C_, psum, psq);
  col_stats_final_f64<<<2, 256, 0, stream>>>(psum, psq, C_, vg, vbe, chpd);
  bn_apply_f64<<<2048, 256, 0, stream>>>(bufY, chpd, bufV);
  // ---- attention (R9-verbatim) ----
  attn_kernel_f64<<<2048, 256, 0, stream>>>(qmask, kmask, bufV, bufO);
  // ---- projection + residual (R9-verbatim) ----
  gemm_nt_f64acc<<<dim3(8,256), 256, 0, stream>>>(bufO, pw, pb, bufY, C_, C_);
  col_stats_partial<<<512, 256, 0, stream>>>(bufY, C_, psum, psq);
  col_stats_final_f64<<<2, 256, 0, stream>>>(psum, psq, C_, pg, pbe, chpd);
  bn_residual_f64<<<2048, 256, 0, stream>>>(bufY, chpd, x, bufO);
  // ---- MLP f1 (bit-identical values, 64x64 retile) ----
  gemm_f32_t64<<<dim3(32,256), 256, 0, stream>>>(bufO, f1w, f1b, bufY, HID_, C_);
  col_stats_partial<<<512, 256, 0, stream>>>(bufY, HID_, psum, psq);
  col_stats_final<<<8, 256, 0, stream>>>(psum, psq, HID_, f1g, f1be, chp);
  bnlif_inplace<<<dim3(8,4096), 256, 0, stream>>>(bufY, chp);
  // ---- MLP f2 (bit-identical values, 64x64 retile) ----
  gemm_f32_t64<<<dim3(8,256), 256, 0, stream>>>(bufY, f2w, f2b, bufV, C_, HID_);
  col_stats_partial<<<512, 256, 0, stream>>>(bufV, C_, psum, psq);
  col_stats_final<<<2, 256, 0, stream>>>(psum, psq, C_, f2g, f2be, chp);
  bnlif_final<<<dim3(2,4096), 256, 0, stream>>>(bufV, chp, bufO, out);
}

// Round 12
// 2077.364 us; speedup vs baseline: 1.0024x; 1.0024x over previous
//
#include <hip/hip_runtime.h>
#include <cstdint>

#define T_ 4
#define B_ 16
#define N_ 256
#define C_ 512
#define H_ 8
#define HID_ 2048
#define M_ (T_*B_*N_)      // 16384 rows
#define BNP_ (B_*N_)       // 4096 (b,n) pairs

// ---------------------------------------------------------------------------
// f32 GEMM, 128x128 tile, 8x8 micro, double-buffered (f1 path).
// BIT-IDENTICAL per-element math to R1: single accumulator, ascending-k
// fmaf chain, plain +bias.
// ---------------------------------------------------------------------------
__global__ __launch_bounds__(256, 2)
void gemm_f32_t128(const float* __restrict__ A, const float* __restrict__ W,
                   const float* __restrict__ bias, float* __restrict__ Y,
                   int Nc, int K) {
  __shared__ float As[2][16][132];
  __shared__ float Ws[2][16][132];
  const int tid  = threadIdx.x;
  const int row0 = blockIdx.y * 128;
  const int col0 = blockIdx.x * 128;
  const int tx = tid & 15, ty = tid >> 4;
  const int ar = tid >> 2;          // 0..63
  const int ac = (tid & 3) << 2;    // 0,4,8,12

  float acc[8][8];
  #pragma unroll
  for (int i = 0; i < 8; ++i)
    #pragma unroll
    for (int j = 0; j < 8; ++j) acc[i][j] = 0.f;

  const float* Ap0 = A + (size_t)(row0 + ar) * K + ac;
  const float* Ap1 = A + (size_t)(row0 + ar + 64) * K + ac;
  const float* Wp0 = W + (size_t)(col0 + ar) * K + ac;
  const float* Wp1 = W + (size_t)(col0 + ar + 64) * K + ac;

  float4 pa0 = *(const float4*)Ap0;
  float4 pa1 = *(const float4*)Ap1;
  float4 pw0 = *(const float4*)Wp0;
  float4 pw1 = *(const float4*)Wp1;
  As[0][ac+0][ar] = pa0.x; As[0][ac+1][ar] = pa0.y; As[0][ac+2][ar] = pa0.z; As[0][ac+3][ar] = pa0.w;
  As[0][ac+0][ar+64] = pa1.x; As[0][ac+1][ar+64] = pa1.y; As[0][ac+2][ar+64] = pa1.z; As[0][ac+3][ar+64] = pa1.w;
  Ws[0][ac+0][ar] = pw0.x; Ws[0][ac+1][ar] = pw0.y; Ws[0][ac+2][ar] = pw0.z; Ws[0][ac+3][ar] = pw0.w;
  Ws[0][ac+0][ar+64] = pw1.x; Ws[0][ac+1][ar+64] = pw1.y; Ws[0][ac+2][ar+64] = pw1.z; Ws[0][ac+3][ar+64] = pw1.w;
  __syncthreads();

  int buf = 0;
  for (int k0 = 0; k0 < K; k0 += 16) {
    const bool last = (k0 + 16 >= K);
    if (!last) {
      pa0 = *(const float4*)(Ap0 + k0 + 16);
      pa1 = *(const float4*)(Ap1 + k0 + 16);
      pw0 = *(const float4*)(Wp0 + k0 + 16);
      pw1 = *(const float4*)(Wp1 + k0 + 16);
    }
    #pragma unroll
    for (int kk = 0; kk < 16; ++kk) {   // ascending k — exact chain order
      float a[8], b[8];
      *(float4*)&a[0] = *(const float4*)&As[buf][kk][ty*8];
      *(float4*)&a[4] = *(const float4*)&As[buf][kk][ty*8+4];
      *(float4*)&b[0] = *(const float4*)&Ws[buf][kk][tx*8];
      *(float4*)&b[4] = *(const float4*)&Ws[buf][kk][tx*8+4];
      #pragma unroll
      for (int i = 0; i < 8; ++i)
        #pragma unroll
        for (int j = 0; j < 8; ++j)
          acc[i][j] = fmaf(a[i], b[j], acc[i][j]);
    }
    if (!last) {
      int nb = buf ^ 1;
      As[nb][ac+0][ar] = pa0.x; As[nb][ac+1][ar] = pa0.y; As[nb][ac+2][ar] = pa0.z; As[nb][ac+3][ar] = pa0.w;
      As[nb][ac+0][ar+64] = pa1.x; As[nb][ac+1][ar+64] = pa1.y; As[nb][ac+2][ar+64] = pa1.z; As[nb][ac+3][ar+64] = pa1.w;
      Ws[nb][ac+0][ar] = pw0.x; Ws[nb][ac+1][ar] = pw0.y; Ws[nb][ac+2][ar] = pw0.z; Ws[nb][ac+3][ar] = pw0.w;
      Ws[nb][ac+0][ar+64] = pw1.x; Ws[nb][ac+1][ar+64] = pw1.y; Ws[nb][ac+2][ar+64] = pw1.z; Ws[nb][ac+3][ar+64] = pw1.w;
      __syncthreads();
      buf = nb;
    }
  }

  #pragma unroll
  for (int i = 0; i < 8; ++i) {
    size_t r = (size_t)(row0 + ty*8 + i);
    #pragma unroll
    for (int j4 = 0; j4 < 2; ++j4) {
      int c = col0 + tx*8 + j4*4;
      float4 o4;
      o4.x = acc[i][j4*4+0] + bias[c+0];
      o4.y = acc[i][j4*4+1] + bias[c+1];
      o4.z = acc[i][j4*4+2] + bias[c+2];
      o4.w = acc[i][j4*4+3] + bias[c+3];
      *(float4*)(Y + r * Nc + c) = o4;
    }
  }
}

// ---------------------------------------------------------------------------
// f32 GEMM, 64(rows)x128(cols) tile, 4x8 micro, double-buffered (q/k/f2).
// Same bit-exact per-element chain. Grid = (Nc/128, M/64) = 1024 blocks.
// ---------------------------------------------------------------------------
__global__ __launch_bounds__(256)
void gemm_f32_t64x128(const float* __restrict__ A, const float* __restrict__ W,
                      const float* __restrict__ bias, float* __restrict__ Y,
                      int Nc, int K) {
  __shared__ float As[2][16][68];
  __shared__ float Ws[2][16][132];
  const int tid  = threadIdx.x;
  const int row0 = blockIdx.y * 64;
  const int col0 = blockIdx.x * 128;
  const int tx = tid & 15, ty = tid >> 4;
  const int ar = tid >> 2;          // 0..63
  const int ac = (tid & 3) << 2;    // 0,4,8,12

  float acc[4][8];
  #pragma unroll
  for (int i = 0; i < 4; ++i)
    #pragma unroll
    for (int j = 0; j < 8; ++j) acc[i][j] = 0.f;

  const float* Ap  = A + (size_t)(row0 + ar) * K + ac;
  const float* Wp0 = W + (size_t)(col0 + ar) * K + ac;
  const float* Wp1 = W + (size_t)(col0 + ar + 64) * K + ac;

  float4 pa  = *(const float4*)Ap;
  float4 pw0 = *(const float4*)Wp0;
  float4 pw1 = *(const float4*)Wp1;
  As[0][ac+0][ar] = pa.x; As[0][ac+1][ar] = pa.y; As[0][ac+2][ar] = pa.z; As[0][ac+3][ar] = pa.w;
  Ws[0][ac+0][ar] = pw0.x; Ws[0][ac+1][ar] = pw0.y; Ws[0][ac+2][ar] = pw0.z; Ws[0][ac+3][ar] = pw0.w;
  Ws[0][ac+0][ar+64] = pw1.x; Ws[0][ac+1][ar+64] = pw1.y; Ws[0][ac+2][ar+64] = pw1.z; Ws[0][ac+3][ar+64] = pw1.w;
  __syncthreads();

  int buf = 0;
  for (int k0 = 0; k0 < K; k0 += 16) {
    const bool last = (k0 + 16 >= K);
    if (!last) {
      pa  = *(const float4*)(Ap  + k0 + 16);
      pw0 = *(const float4*)(Wp0 + k0 + 16);
      pw1 = *(const float4*)(Wp1 + k0 + 16);
    }
    #pragma unroll
    for (int kk = 0; kk < 16; ++kk) {   // ascending k — exact chain order
      float4 av = *(const float4*)&As[buf][kk][ty*4];
      float b[8];
      *(float4*)&b[0] = *(const float4*)&Ws[buf][kk][tx*8];
      *(float4*)&b[4] = *(const float4*)&Ws[buf][kk][tx*8+4];
      float a[4] = {av.x, av.y, av.z, av.w};
      #pragma unroll
      for (int i = 0; i < 4; ++i)
        #pragma unroll
        for (int j = 0; j < 8; ++j)
          acc[i][j] = fmaf(a[i], b[j], acc[i][j]);
    }
    if (!last) {
      int nb = buf ^ 1;
      As[nb][ac+0][ar] = pa.x; As[nb][ac+1][ar] = pa.y; As[nb][ac+2][ar] = pa.z; As[nb][ac+3][ar] = pa.w;
      Ws[nb][ac+0][ar] = pw0.x; Ws[nb][ac+1][ar] = pw0.y; Ws[nb][ac+2][ar] = pw0.z; Ws[nb][ac+3][ar] = pw0.w;
      Ws[nb][ac+0][ar+64] = pw1.x; Ws[nb][ac+1][ar+64] = pw1.y; Ws[nb][ac+2][ar+64] = pw1.z; Ws[nb][ac+3][ar+64] = pw1.w;
      __syncthreads();
      buf = nb;
    }
  }

  #pragma unroll
  for (int i = 0; i < 4; ++i) {
    size_t r = (size_t)(row0 + ty*4 + i);
    #pragma unroll
    for (int j4 = 0; j4 < 2; ++j4) {
      int c = col0 + tx*8 + j4*4;
      float4 o4;
      o4.x = acc[i][j4*4+0] + bias[c+0];
      o4.y = acc[i][j4*4+1] + bias[c+1];
      o4.z = acc[i][j4*4+2] + bias[c+2];
      o4.w = acc[i][j4*4+3] + bias[c+3];
      *(float4*)(Y + r * Nc + c) = o4;
    }
  }
}

// ---------------------------------------------------------------------------
// v/p path GEMM v2: f32 in/out, f64 accumulation. Pre-converted f64 LDS +
// double-buffer + reg prefetch. Per-element chain (ascending-k single-acc
// f64 fma + f64 bias add) IDENTICAL to R9 -> bit-identical outputs.
// ---------------------------------------------------------------------------
__global__ __launch_bounds__(256)
void gemm_f64_v2(const float* __restrict__ A, const float* __restrict__ W,
                 const float* __restrict__ bias, float* __restrict__ Y,
                 int Nc, int K) {
  __shared__ double As[2][16][68];
  __shared__ double Ws[2][16][68];
  const int tid  = threadIdx.x;
  const int row0 = blockIdx.y * 64;
  const int col0 = blockIdx.x * 64;
  const int tx = tid & 15, ty = tid >> 4;
  const int lr = tid >> 2;          // 0..63
  const int lk = (tid & 3) << 2;    // 0,4,8,12

  double acc[4][4];
  #pragma unroll
  for (int i = 0; i < 4; ++i)
    #pragma unroll
    for (int j = 0; j < 4; ++j) acc[i][j] = 0.0;

  const float* Ap = A + (size_t)(row0 + lr) * K + lk;
  const float* Wp = W + (size_t)(col0 + lr) * K + lk;

  float4 pa = *(const float4*)Ap;
  float4 pw = *(const float4*)Wp;
  As[0][lk+0][lr] = (double)pa.x; As[0][lk+1][lr] = (double)pa.y;
  As[0][lk+2][lr] = (double)pa.z; As[0][lk+3][lr] = (double)pa.w;
  Ws[0][lk+0][lr] = (double)pw.x; Ws[0][lk+1][lr] = (double)pw.y;
  Ws[0][lk+2][lr] = (double)pw.z; Ws[0][lk+3][lr] = (double)pw.w;
  __syncthreads();

  int buf = 0;
  for (int k0 = 0; k0 < K; k0 += 16) {
    const bool last = (k0 + 16 >= K);
    if (!last) {
      pa = *(const float4*)(Ap + k0 + 16);
      pw = *(const float4*)(Wp + k0 + 16);
    }
    #pragma unroll
    for (int kk = 0; kk < 16; ++kk) {   // ascending k — exact chain order
      double a[4], b[4];
      *(double2*)&a[0] = *(const double2*)&As[buf][kk][ty*4];
      *(double2*)&a[2] = *(const double2*)&As[buf][kk][ty*4+2];
      *(double2*)&b[0] = *(const double2*)&Ws[buf][kk][tx*4];
      *(double2*)&b[2] = *(const double2*)&Ws[buf][kk][tx*4+2];
      #pragma unroll
      for (int i = 0; i < 4; ++i)
        #pragma unroll
        for (int j = 0; j < 4; ++j)
          acc[i][j] = fma(a[i], b[j], acc[i][j]);
    }
    if (!last) {
      int nb = buf ^ 1;
      As[nb][lk+0][lr] = (double)pa.x; As[nb][lk+1][lr] = (double)pa.y;
      As[nb][lk+2][lr] = (double)pa.z; As[nb][lk+3][lr] = (double)pa.w;
      Ws[nb][lk+0][lr] = (double)pw.x; Ws[nb][lk+1][lr] = (double)pw.y;
      Ws[nb][lk+2][lr] = (double)pw.z; Ws[nb][lk+3][lr] = (double)pw.w;
      __syncthreads();
      buf = nb;
    }
  }

  #pragma unroll
  for (int i = 0; i < 4; ++i) {
    size_t r = (size_t)(row0 + ty*4 + i);
    int c = col0 + tx*4;
    float4 o4;
    o4.x = (float)(acc[i][0] + (double)bias[c+0]);
    o4.y = (float)(acc[i][1] + (double)bias[c+1]);
    o4.z = (float)(acc[i][2] + (double)bias[c+2]);
    o4.w = (float)(acc[i][3] + (double)bias[c+3]);
    *(float4*)(Y + r * Nc + c) = o4;
  }
}

// ---------------------------------------------------------------------------
// BN stats stage 1 (R1-verbatim)
// ---------------------------------------------------------------------------
__global__ __launch_bounds__(256)
void col_stats_partial(const float* __restrict__ Y, int Nc,
                       float* __restrict__ psum, float* __restrict__ psq) {
  const int r0 = blockIdx.x * 32;
  for (int c = threadIdx.x; c < Nc; c += 256) {
    float s = 0.f, q = 0.f;
    const float* p = Y + (size_t)r0 * Nc + c;
    for (int r = 0; r < 32; ++r) {
      float v = p[(size_t)r * Nc];
      s += v;
      q = fmaf(v, v, q);
    }
    psum[(size_t)blockIdx.x * Nc + c] = s;
    psq [(size_t)blockIdx.x * Nc + c] = q;
  }
}

// stage 2 (R1-verbatim): f32 chp for q/k/f1/f2 paths
__global__ void col_stats_final(const float* __restrict__ psum, const float* __restrict__ psq,
                                int Nc, const float* __restrict__ g, const float* __restrict__ beta,
                                float* __restrict__ chp) {
  int c = blockIdx.x * blockDim.x + threadIdx.x;
  if (c >= Nc) return;
  double s = 0.0, q = 0.0;
  for (int p = 0; p < 512; ++p) {
    s += (double)psum[(size_t)p * Nc + c];
    q += (double)psq [(size_t)p * Nc + c];
  }
  double mean = s / (double)M_;
  double var  = q / (double)M_ - mean * mean;
  float alpha = g[c] / sqrtf((float)var + 1e-5f);
  chp[2*c]   = alpha;
  chp[2*c+1] = fmaf(-(float)mean, alpha, beta[c]);   // beta - mean*alpha
}

// stage 2 for v/p paths: f64 affine params (R9-verbatim)
__global__ void col_stats_final_f64(const float* __restrict__ psum, const float* __restrict__ psq,
                                    int Nc, const float* __restrict__ g, const float* __restrict__ beta,
                                    double* __restrict__ chpd) {
  int c = blockIdx.x * blockDim.x + threadIdx.x;
  if (c >= Nc) return;
  double s = 0.0, q = 0.0;
  for (int p = 0; p < 512; ++p) {
    s += (double)psum[(size_t)p * Nc + c];
    q += (double)psq [(size_t)p * Nc + c];
  }
  double mean = s / (double)M_;
  double var  = q / (double)M_ - mean * mean;
  double alpha = (double)g[c] / sqrt(var + 1e-5);
  chpd[2*c]   = alpha;
  chpd[2*c+1] = (double)beta[c] - mean * alpha;
}

// ---------------------------------------------------------------------------
// BN + LIF masks (R1-verbatim) — q/k decisions, frozen
// ---------------------------------------------------------------------------
__global__ __launch_bounds__(256)
void bnlif_mask(const float* __restrict__ Y, const float* __restrict__ chp,
                unsigned long long* __restrict__ mask) {
  int lane = threadIdx.x & 63;
  int u  = blockIdx.x * 4 + (threadIdx.x >> 6);
  int bn = u >> 3, cg = u & 7;          // cg == head (Dh==64)
  int c  = cg * 64 + lane;
  float alpha = chp[2*c], bb = chp[2*c+1];
  float v = 0.f;
  #pragma unroll
  for (int t = 0; t < 4; ++t) {
    float y  = Y[((size_t)(t * BNP_ + bn)) * C_ + c];
    float uu = fmaf(y, alpha, bb);
    v = v + (uu - v) * 0.5f;            // v += (x - v)/tau, tau=2
    bool sp = (v >= 1.0f);
    unsigned long long m = __ballot(sp);
    if (sp) v = 0.f;                    // hard reset
    if (lane == 0) mask[((size_t)(t * BNP_ + bn)) * H_ + cg] = m;
  }
}

// BN apply (v path), f64 math → f32 out (R9-verbatim)
__global__ void bn_apply_f64(const float* __restrict__ Y, const double* __restrict__ chpd,
                             float* __restrict__ out) {
  const long total4 = (long)M_ * C_ / 4;
  for (long i = (long)blockIdx.x * blockDim.x + threadIdx.x; i < total4;
       i += (long)gridDim.x * blockDim.x) {
    int c4 = (int)(i & (C_/4 - 1)) * 4;
    float4 y = ((const float4*)Y)[i];
    float4 r;
    r.x = (float)fma((double)y.x, chpd[2*(c4+0)], chpd[2*(c4+0)+1]);
    r.y = (float)fma((double)y.y, chpd[2*(c4+1)], chpd[2*(c4+1)+1]);
    r.z = (float)fma((double)y.z, chpd[2*(c4+2)], chpd[2*(c4+2)+1]);
    r.w = (float)fma((double)y.w, chpd[2*(c4+3)], chpd[2*(c4+3)+1]);
    ((float4*)out)[i] = r;
  }
}

// xo = x + BN(Yp), f64 math → f32 out (R9-verbatim)
__global__ void bn_residual_f64(const float* __restrict__ Y, const double* __restrict__ chpd,
                                const float* __restrict__ x, float* __restrict__ out) {
  const long total4 = (long)M_ * C_ / 4;
  for (long i = (long)blockIdx.x * blockDim.x + threadIdx.x; i < total4;
       i += (long)gridDim.x * blockDim.x) {
    int c4 = (int)(i & (C_/4 - 1)) * 4;
    float4 y = ((const float4*)Y)[i];
    float4 xv = ((const float4*)x)[i];
    float4 r;
    r.x = (float)((double)xv.x + fma((double)y.x, chpd[2*(c4+0)], chpd[2*(c4+0)+1]));
    r.y = (float)((double)xv.y + fma((double)y.y, chpd[2*(c4+1)], chpd[2*(c4+1)+1]));
    r.z = (float)((double)xv.z + fma((double)y.z, chpd[2*(c4+2)], chpd[2*(c4+2)+1]));
    r.w = (float)((double)xv.w + fma((double)y.w, chpd[2*(c4+3)], chpd[2*(c4+3)+1]));
    ((float4*)out)[i] = r;
  }
}

// BN + LIF for f1 (R1-verbatim), spikes in place as 1.0f/0.0f
__global__ __launch_bounds__(256)
void bnlif_inplace(float* __restrict__ Y, const float* __restrict__ chp) {
  int c  = blockIdx.x * 256 + threadIdx.x;   // < 2048
  int bn = blockIdx.y;
  float alpha = chp[2*c], bb = chp[2*c+1];
  float v = 0.f;
  #pragma unroll
  for (int t = 0; t < 4; ++t) {
    size_t idx = ((size_t)(t * BNP_ + bn)) * HID_ + c;
    float uu = fmaf(Y[idx], alpha, bb);
    v = v + (uu - v) * 0.5f;
    bool sp = (v >= 1.f);
    Y[idx] = sp ? 1.f : 0.f;
    if (sp) v = 0.f;
  }
}

// BN + LIF for f2 + final residual (R1-verbatim)
__global__ __launch_bounds__(256)
void bnlif_final(const float* __restrict__ Y, const float* __restrict__ chp,
                 const float* __restrict__ xo, float* __restrict__ out) {
  int c  = blockIdx.x * 256 + threadIdx.x;   // < 512
  int bn = blockIdx.y;
  float alpha = chp[2*c], bb = chp[2*c+1];
  float v = 0.f;
  #pragma unroll
  for (int t = 0; t < 4; ++t) {
    size_t idx = ((size_t)(t * BNP_ + bn)) * C_ + c;
    float uu = fmaf(Y[idx], alpha, bb);
    v = v + (uu - v) * 0.5f;
    bool sp = (v >= 1.f);
    out[idx] = xo[idx] + (sp ? 1.f : 0.f);
    if (sp) v = 0.f;
  }
}

// ---------------------------------------------------------------------------
// Attention (R9-verbatim): popcount QK (exact); PV accumulated in f64.
// ---------------------------------------------------------------------------
__global__ __launch_bounds__(256)
void attn_kernel_f64(const unsigned long long* __restrict__ qmask,
                     const unsigned long long* __restrict__ kmask,
                     const float* __restrict__ v, float* __restrict__ o) {
  __shared__ unsigned long long km[256];
  __shared__ float vt[256][64];
  int rb  = blockIdx.x & 3;
  int tbh = blockIdx.x >> 2;
  int h   = tbh & 7, tb = tbh >> 3;     // tb = t*16+b
  int tid = threadIdx.x;

  km[tid] = kmask[(size_t)(tb * 256 + tid) * H_ + h];
  const float* vbase = v + (size_t)tb * 256 * C_ + h * 64;
  #pragma unroll
  for (int i = 0; i < 16; ++i) {
    int f = i * 256 + tid;
    int r = f >> 4, c4 = f & 15;
    *(float4*)&vt[r][c4 * 4] = *(const float4*)(vbase + (size_t)r * C_ + c4 * 4);
  }
  int lane = tid & 63, w = tid >> 6;
  int nr = lane & 15, dg = lane >> 4;
  int n  = rb * 64 + w * 16 + nr;
  unsigned long long qm = qmask[(size_t)(tb * 256 + n) * H_ + h];
  __syncthreads();

  double acc[16];
  #pragma unroll
  for (int j = 0; j < 16; ++j) acc[j] = 0.0;

  for (int m = 0; m < 256; ++m) {
    double s = (double)__popcll(qm & km[m]) * 0.125;   // exact
    #pragma unroll
    for (int j = 0; j < 4; ++j) {
      float4 vv = *(const float4*)&vt[m][dg * 16 + j * 4];
      acc[j*4+0] = fma(s, (double)vv.x, acc[j*4+0]);
      acc[j*4+1] = fma(s, (double)vv.y, acc[j*4+1]);
      acc[j*4+2] = fma(s, (double)vv.z, acc[j*4+2]);
      acc[j*4+3] = fma(s, (double)vv.w, acc[j*4+3]);
    }
  }
  float* orow = o + (size_t)(tb * 256 + n) * C_ + h * 64 + dg * 16;
  #pragma unroll
  for (int j = 0; j < 4; ++j)
    *(float4*)(orow + j * 4) = make_float4((float)acc[j*4], (float)acc[j*4+1],
                                           (float)acc[j*4+2], (float)acc[j*4+3]);
}

// ---------------------------------------------------------------------------
extern "C" void kernel_launch(void* const* d_in, const int* in_sizes, int n_in,
                              void* d_out, int out_size, void* d_ws, size_t ws_size,
                              hipStream_t stream) {
  const float* x    = (const float*)d_in[0];
  const float* qw   = (const float*)d_in[2];
  const float* qb   = (const float*)d_in[3];
  const float* qg   = (const float*)d_in[4];
  const float* qbe  = (const float*)d_in[5];
  const float* kw   = (const float*)d_in[6];
  const float* kb   = (const float*)d_in[7];
  const float* kg   = (const float*)d_in[8];
  const float* kbe  = (const float*)d_in[9];
  const float* vw   = (const float*)d_in[10];
  const float* vb   = (const float*)d_in[11];
  const float* vg   = (const float*)d_in[12];
  const float* vbe  = (const float*)d_in[13];
  const float* pw   = (const float*)d_in[14];
  const float* pb   = (const float*)d_in[15];
  const float* pg   = (const float*)d_in[16];
  const float* pbe  = (const float*)d_in[17];
  const float* f1w  = (const float*)d_in[18];
  const float* f1b  = (const float*)d_in[19];
  const float* f1g  = (const float*)d_in[20];
  const float* f1be = (const float*)d_in[21];
  const float* f2w  = (const float*)d_in[22];
  const float* f2b  = (const float*)d_in[23];
  const float* f2g  = (const float*)d_in[24];
  const float* f2be = (const float*)d_in[25];

  char* ws = (char*)d_ws;
  float* bufY = (float*)(ws);                                   // 128 MB (16384x2048 f32)
  float* bufV = (float*)(ws + 134217728ull);                    //  32 MB
  float* bufO = (float*)(ws + 167772160ull);                    //  32 MB (o, then xo)
  unsigned long long* qmask = (unsigned long long*)(ws + 201326592ull);  // 1 MB
  unsigned long long* kmask = (unsigned long long*)(ws + 202375168ull);  // 1 MB
  float* psum = (float*)(ws + 203423744ull);                    // 4 MB (512 x 2048)
  float* psq  = (float*)(ws + 207618048ull);                    // 4 MB
  float* chp  = (float*)(ws + 211812352ull);                    // 16 KB
  double* chpd = (double*)(ws + 211828736ull);                  // 8 KB

  float* out = (float*)d_out;

  // ---- q path (bit-identical values, 64x128 retile) ----
  gemm_f32_t64x128<<<dim3(4,256), 256, 0, stream>>>(x, qw, qb, bufY, C_, C_);
  col_stats_partial<<<512, 256, 0, stream>>>(bufY, C_, psum, psq);
  col_stats_final<<<2, 256, 0, stream>>>(psum, psq, C_, qg, qbe, chp);
  bnlif_mask<<<8192, 256, 0, stream>>>(bufY, chp, qmask);
  // ---- k path ----
  gemm_f32_t64x128<<<dim3(4,256), 256, 0, stream>>>(x, kw, kb, bufY, C_, C_);
  col_stats_partial<<<512, 256, 0, stream>>>(bufY, C_, psum, psq);
  col_stats_final<<<2, 256, 0, stream>>>(psum, psq, C_, kg, kbe, chp);
  bnlif_mask<<<8192, 256, 0, stream>>>(bufY, chp, kmask);
  // ---- v path (f64-internal, dbuf retile — bit-identical chain) ----
  gemm_f64_v2<<<dim3(8,256), 256, 0, stream>>>(x, vw, vb, bufY, C_, C_);
  col_stats_partial<<<512, 256, 0, stream>>>(bufY, C_, psum, psq);
  col_stats_final_f64<<<2, 256, 0, stream>>>(psum, psq, C_, vg, vbe, chpd);
  bn_apply_f64<<<2048, 256, 0, stream>>>(bufY, chpd, bufV);
  // ---- attention (R9-verbatim) ----
  attn_kernel_f64<<<2048, 256, 0, stream>>>(qmask, kmask, bufV, bufO);
  // ---- projection + residual (f64-internal, dbuf retile) ----
  gemm_f64_v2<<<dim3(8,256), 256, 0, stream>>>(bufO, pw, pb, bufY, C_, C_);
  col_stats_partial<<<512, 256, 0, stream>>>(bufY, C_, psum, psq);
  col_stats_final_f64<<<2, 256, 0, stream>>>(psum, psq, C_, pg, pbe, chpd);
  bn_residual_f64<<<2048, 256, 0, stream>>>(bufY, chpd, x, bufO);
  // ---- MLP f1 (bit-identical values, 128x128 dbuf retile) ----
  gemm_f32_t128<<<dim3(16,128), 256, 0, stream>>>(bufO, f1w, f1b, bufY, HID_, C_);
  col_stats_partial<<<512, 256, 0, stream>>>(bufY, HID_, psum, psq);
  col_stats_final<<<8, 256, 0, stream>>>(psum, psq, HID_, f1g, f1be, chp);
  bnlif_inplace<<<dim3(8,4096), 256, 0, stream>>>(bufY, chp);
  // ---- MLP f2 (bit-identical values, 64x128 retile) ----
  gemm_f32_t64x128<<<dim3(4,256), 256, 0, stream>>>(bufY, f2w, f2b, bufV, C_, HID_);
  col_stats_partial<<<512, 256, 0, stream>>>(bufV, C_, psum, psq);
  col_stats_final<<<2, 256, 0, stream>>>(psum, psq, C_, f2g, f2be, chp);
  bnlif_final<<<dim3(2,4096), 256, 0, stream>>>(bufV, chp, bufO, out);
}

// Round 13
// 1982.326 us; speedup vs baseline: 1.0505x; 1.0479x over previous
//
#include <hip/hip_runtime.h>
#include <cstdint>

#define T_ 4
#define B_ 16
#define N_ 256
#define C_ 512
#define H_ 8
#define HID_ 2048
#define M_ (T_*B_*N_)      // 16384 rows
#define BNP_ (B_*N_)       // 4096 (b,n) pairs

// ---------------------------------------------------------------------------
// f32 GEMM, 128x128 tile, 8x8 micro, double-buffered, CONFLICT-FREE fragment
// map: rows {ty*4, 64+ty*4}, cols {tx*4, 64+tx*4} (16B-stride ds_reads = 2-way
// = free). BIT-IDENTICAL per-element math to R1: single accumulator,
// ascending-k fmaf chain, plain +bias.
// ---------------------------------------------------------------------------
__global__ __launch_bounds__(256, 2)
void gemm_f32_t128(const float* __restrict__ A, const float* __restrict__ W,
                   const float* __restrict__ bias, float* __restrict__ Y,
                   int Nc, int K) {
  __shared__ float As[2][16][132];
  __shared__ float Ws[2][16][132];
  const int tid  = threadIdx.x;
  const int row0 = blockIdx.y * 128;
  const int col0 = blockIdx.x * 128;
  const int tx = tid & 15, ty = tid >> 4;
  const int ar = tid >> 2;          // 0..63
  const int ac = (tid & 3) << 2;    // 0,4,8,12

  float acc[8][8];                  // [ih*4+i][jh*4+j]
  #pragma unroll
  for (int i = 0; i < 8; ++i)
    #pragma unroll
    for (int j = 0; j < 8; ++j) acc[i][j] = 0.f;

  const float* Ap0 = A + (size_t)(row0 + ar) * K + ac;
  const float* Ap1 = A + (size_t)(row0 + ar + 64) * K + ac;
  const float* Wp0 = W + (size_t)(col0 + ar) * K + ac;
  const float* Wp1 = W + (size_t)(col0 + ar + 64) * K + ac;

  float4 pa0 = *(const float4*)Ap0;
  float4 pa1 = *(const float4*)Ap1;
  float4 pw0 = *(const float4*)Wp0;
  float4 pw1 = *(const float4*)Wp1;
  As[0][ac+0][ar] = pa0.x; As[0][ac+1][ar] = pa0.y; As[0][ac+2][ar] = pa0.z; As[0][ac+3][ar] = pa0.w;
  As[0][ac+0][ar+64] = pa1.x; As[0][ac+1][ar+64] = pa1.y; As[0][ac+2][ar+64] = pa1.z; As[0][ac+3][ar+64] = pa1.w;
  Ws[0][ac+0][ar] = pw0.x; Ws[0][ac+1][ar] = pw0.y; Ws[0][ac+2][ar] = pw0.z; Ws[0][ac+3][ar] = pw0.w;
  Ws[0][ac+0][ar+64] = pw1.x; Ws[0][ac+1][ar+64] = pw1.y; Ws[0][ac+2][ar+64] = pw1.z; Ws[0][ac+3][ar+64] = pw1.w;
  __syncthreads();

  int buf = 0;
  for (int k0 = 0; k0 < K; k0 += 16) {
    const bool last = (k0 + 16 >= K);
    if (!last) {
      pa0 = *(const float4*)(Ap0 + k0 + 16);
      pa1 = *(const float4*)(Ap1 + k0 + 16);
      pw0 = *(const float4*)(Wp0 + k0 + 16);
      pw1 = *(const float4*)(Wp1 + k0 + 16);
    }
    #pragma unroll
    for (int kk = 0; kk < 16; ++kk) {   // ascending k — exact chain order
      float a[8], b[8];
      *(float4*)&a[0] = *(const float4*)&As[buf][kk][ty*4];
      *(float4*)&a[4] = *(const float4*)&As[buf][kk][64 + ty*4];
      *(float4*)&b[0] = *(const float4*)&Ws[buf][kk][tx*4];
      *(float4*)&b[4] = *(const float4*)&Ws[buf][kk][64 + tx*4];
      #pragma unroll
      for (int i = 0; i < 8; ++i)
        #pragma unroll
        for (int j = 0; j < 8; ++j)
          acc[i][j] = fmaf(a[i], b[j], acc[i][j]);
    }
    if (!last) {
      int nb = buf ^ 1;
      As[nb][ac+0][ar] = pa0.x; As[nb][ac+1][ar] = pa0.y; As[nb][ac+2][ar] = pa0.z; As[nb][ac+3][ar] = pa0.w;
      As[nb][ac+0][ar+64] = pa1.x; As[nb][ac+1][ar+64] = pa1.y; As[nb][ac+2][ar+64] = pa1.z; As[nb][ac+3][ar+64] = pa1.w;
      Ws[nb][ac+0][ar] = pw0.x; Ws[nb][ac+1][ar] = pw0.y; Ws[nb][ac+2][ar] = pw0.z; Ws[nb][ac+3][ar] = pw0.w;
      Ws[nb][ac+0][ar+64] = pw1.x; Ws[nb][ac+1][ar+64] = pw1.y; Ws[nb][ac+2][ar+64] = pw1.z; Ws[nb][ac+3][ar+64] = pw1.w;
      __syncthreads();
      buf = nb;
    }
  }

  #pragma unroll
  for (int ih = 0; ih < 2; ++ih)
    #pragma unroll
    for (int i = 0; i < 4; ++i) {
      size_t r = (size_t)(row0 + ih*64 + ty*4 + i);
      #pragma unroll
      for (int jh = 0; jh < 2; ++jh) {
        int c = col0 + jh*64 + tx*4;
        float4 o4;
        o4.x = acc[ih*4+i][jh*4+0] + bias[c+0];
        o4.y = acc[ih*4+i][jh*4+1] + bias[c+1];
        o4.z = acc[ih*4+i][jh*4+2] + bias[c+2];
        o4.w = acc[ih*4+i][jh*4+3] + bias[c+3];
        *(float4*)(Y + r * Nc + c) = o4;
      }
    }
}

// ---------------------------------------------------------------------------
// f32 GEMM, 64x128 tile, 4x8 micro, double-buffered, conflict-free cols
// {tx*4, 64+tx*4}. Same bit-exact per-element chain. (q/k/f2)
// ---------------------------------------------------------------------------
__global__ __launch_bounds__(256)
void gemm_f32_t64x128(const float* __restrict__ A, const float* __restrict__ W,
                      const float* __restrict__ bias, float* __restrict__ Y,
                      int Nc, int K) {
  __shared__ float As[2][16][68];
  __shared__ float Ws[2][16][132];
  const int tid  = threadIdx.x;
  const int row0 = blockIdx.y * 64;
  const int col0 = blockIdx.x * 128;
  const int tx = tid & 15, ty = tid >> 4;
  const int ar = tid >> 2;          // 0..63
  const int ac = (tid & 3) << 2;    // 0,4,8,12

  float acc[4][8];                  // [i][jh*4+j]
  #pragma unroll
  for (int i = 0; i < 4; ++i)
    #pragma unroll
    for (int j = 0; j < 8; ++j) acc[i][j] = 0.f;

  const float* Ap  = A + (size_t)(row0 + ar) * K + ac;
  const float* Wp0 = W + (size_t)(col0 + ar) * K + ac;
  const float* Wp1 = W + (size_t)(col0 + ar + 64) * K + ac;

  float4 pa  = *(const float4*)Ap;
  float4 pw0 = *(const float4*)Wp0;
  float4 pw1 = *(const float4*)Wp1;
  As[0][ac+0][ar] = pa.x; As[0][ac+1][ar] = pa.y; As[0][ac+2][ar] = pa.z; As[0][ac+3][ar] = pa.w;
  Ws[0][ac+0][ar] = pw0.x; Ws[0][ac+1][ar] = pw0.y; Ws[0][ac+2][ar] = pw0.z; Ws[0][ac+3][ar] = pw0.w;
  Ws[0][ac+0][ar+64] = pw1.x; Ws[0][ac+1][ar+64] = pw1.y; Ws[0][ac+2][ar+64] = pw1.z; Ws[0][ac+3][ar+64] = pw1.w;
  __syncthreads();

  int buf = 0;
  for (int k0 = 0; k0 < K; k0 += 16) {
    const bool last = (k0 + 16 >= K);
    if (!last) {
      pa  = *(const float4*)(Ap  + k0 + 16);
      pw0 = *(const float4*)(Wp0 + k0 + 16);
      pw1 = *(const float4*)(Wp1 + k0 + 16);
    }
    #pragma unroll
    for (int kk = 0; kk < 16; ++kk) {   // ascending k — exact chain order
      float4 av = *(const float4*)&As[buf][kk][ty*4];
      float b[8];
      *(float4*)&b[0] = *(const float4*)&Ws[buf][kk][tx*4];
      *(float4*)&b[4] = *(const float4*)&Ws[buf][kk][64 + tx*4];
      float a[4] = {av.x, av.y, av.z, av.w};
      #pragma unroll
      for (int i = 0; i < 4; ++i)
        #pragma unroll
        for (int j = 0; j < 8; ++j)
          acc[i][j] = fmaf(a[i], b[j], acc[i][j]);
    }
    if (!last) {
      int nb = buf ^ 1;
      As[nb][ac+0][ar] = pa.x; As[nb][ac+1][ar] = pa.y; As[nb][ac+2][ar] = pa.z; As[nb][ac+3][ar] = pa.w;
      Ws[nb][ac+0][ar] = pw0.x; Ws[nb][ac+1][ar] = pw0.y; Ws[nb][ac+2][ar] = pw0.z; Ws[nb][ac+3][ar] = pw0.w;
      Ws[nb][ac+0][ar+64] = pw1.x; Ws[nb][ac+1][ar+64] = pw1.y; Ws[nb][ac+2][ar+64] = pw1.z; Ws[nb][ac+3][ar+64] = pw1.w;
      __syncthreads();
      buf = nb;
    }
  }

  #pragma unroll
  for (int i = 0; i < 4; ++i) {
    size_t r = (size_t)(row0 + ty*4 + i);
    #pragma unroll
    for (int jh = 0; jh < 2; ++jh) {
      int c = col0 + jh*64 + tx*4;
      float4 o4;
      o4.x = acc[i][jh*4+0] + bias[c+0];
      o4.y = acc[i][jh*4+1] + bias[c+1];
      o4.z = acc[i][jh*4+2] + bias[c+2];
      o4.w = acc[i][jh*4+3] + bias[c+3];
      *(float4*)(Y + r * Nc + c) = o4;
    }
  }
}

// ---------------------------------------------------------------------------
// v/p path GEMM: f32 in/out, f64 accumulation, conflict-free cols
// {tx*2, 32+tx*2}. Per-element chain IDENTICAL to R9 -> bit-identical.
// ---------------------------------------------------------------------------
__global__ __launch_bounds__(256)
void gemm_f64_v2(const float* __restrict__ A, const float* __restrict__ W,
                 const float* __restrict__ bias, float* __restrict__ Y,
                 int Nc, int K) {
  __shared__ double As[2][16][68];
  __shared__ double Ws[2][16][68];
  const int tid  = threadIdx.x;
  const int row0 = blockIdx.y * 64;
  const int col0 = blockIdx.x * 64;
  const int tx = tid & 15, ty = tid >> 4;
  const int lr = tid >> 2;          // 0..63
  const int lk = (tid & 3) << 2;    // 0,4,8,12

  double acc[4][4];                 // cols {tx*2, tx*2+1, 32+tx*2, 32+tx*2+1}
  #pragma unroll
  for (int i = 0; i < 4; ++i)
    #pragma unroll
    for (int j = 0; j < 4; ++j) acc[i][j] = 0.0;

  const float* Ap = A + (size_t)(row0 + lr) * K + lk;
  const float* Wp = W + (size_t)(col0 + lr) * K + lk;

  float4 pa = *(const float4*)Ap;
  float4 pw = *(const float4*)Wp;
  As[0][lk+0][lr] = (double)pa.x; As[0][lk+1][lr] = (double)pa.y;
  As[0][lk+2][lr] = (double)pa.z; As[0][lk+3][lr] = (double)pa.w;
  Ws[0][lk+0][lr] = (double)pw.x; Ws[0][lk+1][lr] = (double)pw.y;
  Ws[0][lk+2][lr] = (double)pw.z; Ws[0][lk+3][lr] = (double)pw.w;
  __syncthreads();

  int buf = 0;
  for (int k0 = 0; k0 < K; k0 += 16) {
    const bool last = (k0 + 16 >= K);
    if (!last) {
      pa = *(const float4*)(Ap + k0 + 16);
      pw = *(const float4*)(Wp + k0 + 16);
    }
    #pragma unroll
    for (int kk = 0; kk < 16; ++kk) {   // ascending k — exact chain order
      double a[4], b[4];
      *(double2*)&a[0] = *(const double2*)&As[buf][kk][ty*4];
      *(double2*)&a[2] = *(const double2*)&As[buf][kk][ty*4+2];
      *(double2*)&b[0] = *(const double2*)&Ws[buf][kk][tx*2];
      *(double2*)&b[2] = *(const double2*)&Ws[buf][kk][32 + tx*2];
      #pragma unroll
      for (int i = 0; i < 4; ++i)
        #pragma unroll
        for (int j = 0; j < 4; ++j)
          acc[i][j] = fma(a[i], b[j], acc[i][j]);
    }
    if (!last) {
      int nb = buf ^ 1;
      As[nb][lk+0][lr] = (double)pa.x; As[nb][lk+1][lr] = (double)pa.y;
      As[nb][lk+2][lr] = (double)pa.z; As[nb][lk+3][lr] = (double)pa.w;
      Ws[nb][lk+0][lr] = (double)pw.x; Ws[nb][lk+1][lr] = (double)pw.y;
      Ws[nb][lk+2][lr] = (double)pw.z; Ws[nb][lk+3][lr] = (double)pw.w;
      __syncthreads();
      buf = nb;
    }
  }

  #pragma unroll
  for (int i = 0; i < 4; ++i) {
    size_t r = (size_t)(row0 + ty*4 + i);
    int c0 = col0 + tx*2;
    float2 o0;
    o0.x = (float)(acc[i][0] + (double)bias[c0+0]);
    o0.y = (float)(acc[i][1] + (double)bias[c0+1]);
    *(float2*)(Y + r * Nc + c0) = o0;
    int c1 = col0 + 32 + tx*2;
    float2 o1;
    o1.x = (float)(acc[i][2] + (double)bias[c1+0]);
    o1.y = (float)(acc[i][3] + (double)bias[c1+1]);
    *(float2*)(Y + r * Nc + c1) = o1;
  }
}

// ---------------------------------------------------------------------------
// BN stats stage 1 (R1-verbatim)
// ---------------------------------------------------------------------------
__global__ __launch_bounds__(256)
void col_stats_partial(const float* __restrict__ Y, int Nc,
                       float* __restrict__ psum, float* __restrict__ psq) {
  const int r0 = blockIdx.x * 32;
  for (int c = threadIdx.x; c < Nc; c += 256) {
    float s = 0.f, q = 0.f;
    const float* p = Y + (size_t)r0 * Nc + c;
    for (int r = 0; r < 32; ++r) {
      float v = p[(size_t)r * Nc];
      s += v;
      q = fmaf(v, v, q);
    }
    psum[(size_t)blockIdx.x * Nc + c] = s;
    psq [(size_t)blockIdx.x * Nc + c] = q;
  }
}

// stage 2 (R1-verbatim): f32 chp for q/k/f1/f2 paths
__global__ void col_stats_final(const float* __restrict__ psum, const float* __restrict__ psq,
                                int Nc, const float* __restrict__ g, const float* __restrict__ beta,
                                float* __restrict__ chp) {
  int c = blockIdx.x * blockDim.x + threadIdx.x;
  if (c >= Nc) return;
  double s = 0.0, q = 0.0;
  for (int p = 0; p < 512; ++p) {
    s += (double)psum[(size_t)p * Nc + c];
    q += (double)psq [(size_t)p * Nc + c];
  }
  double mean = s / (double)M_;
  double var  = q / (double)M_ - mean * mean;
  float alpha = g[c] / sqrtf((float)var + 1e-5f);
  chp[2*c]   = alpha;
  chp[2*c+1] = fmaf(-(float)mean, alpha, beta[c]);   // beta - mean*alpha
}

// stage 2 for v/p paths: f64 affine params (R9-verbatim)
__global__ void col_stats_final_f64(const float* __restrict__ psum, const float* __restrict__ psq,
                                    int Nc, const float* __restrict__ g, const float* __restrict__ beta,
                                    double* __restrict__ chpd) {
  int c = blockIdx.x * blockDim.x + threadIdx.x;
  if (c >= Nc) return;
  double s = 0.0, q = 0.0;
  for (int p = 0; p < 512; ++p) {
    s += (double)psum[(size_t)p * Nc + c];
    q += (double)psq [(size_t)p * Nc + c];
  }
  double mean = s / (double)M_;
  double var  = q / (double)M_ - mean * mean;
  double alpha = (double)g[c] / sqrt(var + 1e-5);
  chpd[2*c]   = alpha;
  chpd[2*c+1] = (double)beta[c] - mean * alpha;
}

// ---------------------------------------------------------------------------
// BN + LIF masks (R1-verbatim) — q/k decisions, frozen
// ---------------------------------------------------------------------------
__global__ __launch_bounds__(256)
void bnlif_mask(const float* __restrict__ Y, const float* __restrict__ chp,
                unsigned long long* __restrict__ mask) {
  int lane = threadIdx.x & 63;
  int u  = blockIdx.x * 4 + (threadIdx.x >> 6);
  int bn = u >> 3, cg = u & 7;          // cg == head (Dh==64)
  int c  = cg * 64 + lane;
  float alpha = chp[2*c], bb = chp[2*c+1];
  float v = 0.f;
  #pragma unroll
  for (int t = 0; t < 4; ++t) {
    float y  = Y[((size_t)(t * BNP_ + bn)) * C_ + c];
    float uu = fmaf(y, alpha, bb);
    v = v + (uu - v) * 0.5f;            // v += (x - v)/tau, tau=2
    bool sp = (v >= 1.0f);
    unsigned long long m = __ballot(sp);
    if (sp) v = 0.f;                    // hard reset
    if (lane == 0) mask[((size_t)(t * BNP_ + bn)) * H_ + cg] = m;
  }
}

// BN apply (v path), f64 math → f32 out (R9-verbatim)
__global__ void bn_apply_f64(const float* __restrict__ Y, const double* __restrict__ chpd,
                             float* __restrict__ out) {
  const long total4 = (long)M_ * C_ / 4;
  for (long i = (long)blockIdx.x * blockDim.x + threadIdx.x; i < total4;
       i += (long)gridDim.x * blockDim.x) {
    int c4 = (int)(i & (C_/4 - 1)) * 4;
    float4 y = ((const float4*)Y)[i];
    float4 r;
    r.x = (float)fma((double)y.x, chpd[2*(c4+0)], chpd[2*(c4+0)+1]);
    r.y = (float)fma((double)y.y, chpd[2*(c4+1)], chpd[2*(c4+1)+1]);
    r.z = (float)fma((double)y.z, chpd[2*(c4+2)], chpd[2*(c4+2)+1]);
    r.w = (float)fma((double)y.w, chpd[2*(c4+3)], chpd[2*(c4+3)+1]);
    ((float4*)out)[i] = r;
  }
}

// xo = x + BN(Yp), f64 math → f32 out (R9-verbatim)
__global__ void bn_residual_f64(const float* __restrict__ Y, const double* __restrict__ chpd,
                                const float* __restrict__ x, float* __restrict__ out) {
  const long total4 = (long)M_ * C_ / 4;
  for (long i = (long)blockIdx.x * blockDim.x + threadIdx.x; i < total4;
       i += (long)gridDim.x * blockDim.x) {
    int c4 = (int)(i & (C_/4 - 1)) * 4;
    float4 y = ((const float4*)Y)[i];
    float4 xv = ((const float4*)x)[i];
    float4 r;
    r.x = (float)((double)xv.x + fma((double)y.x, chpd[2*(c4+0)], chpd[2*(c4+0)+1]));
    r.y = (float)((double)xv.y + fma((double)y.y, chpd[2*(c4+1)], chpd[2*(c4+1)+1]));
    r.z = (float)((double)xv.z + fma((double)y.z, chpd[2*(c4+2)], chpd[2*(c4+2)+1]));
    r.w = (float)((double)xv.w + fma((double)y.w, chpd[2*(c4+3)], chpd[2*(c4+3)+1]));
    ((float4*)out)[i] = r;
  }
}

// BN + LIF for f1 (R1-verbatim), spikes in place as 1.0f/0.0f
__global__ __launch_bounds__(256)
void bnlif_inplace(float* __restrict__ Y, const float* __restrict__ chp) {
  int c  = blockIdx.x * 256 + threadIdx.x;   // < 2048
  int bn = blockIdx.y;
  float alpha = chp[2*c], bb = chp[2*c+1];
  float v = 0.f;
  #pragma unroll
  for (int t = 0; t < 4; ++t) {
    size_t idx = ((size_t)(t * BNP_ + bn)) * HID_ + c;
    float uu = fmaf(Y[idx], alpha, bb);
    v = v + (uu - v) * 0.5f;
    bool sp = (v >= 1.f);
    Y[idx] = sp ? 1.f : 0.f;
    if (sp) v = 0.f;
  }
}

// BN + LIF for f2 + final residual (R1-verbatim)
__global__ __launch_bounds__(256)
void bnlif_final(const float* __restrict__ Y, const float* __restrict__ chp,
                 const float* __restrict__ xo, float* __restrict__ out) {
  int c  = blockIdx.x * 256 + threadIdx.x;   // < 512
  int bn = blockIdx.y;
  float alpha = chp[2*c], bb = chp[2*c+1];
  float v = 0.f;
  #pragma unroll
  for (int t = 0; t < 4; ++t) {
    size_t idx = ((size_t)(t * BNP_ + bn)) * C_ + c;
    float uu = fmaf(Y[idx], alpha, bb);
    v = v + (uu - v) * 0.5f;
    bool sp = (v >= 1.f);
    out[idx] = xo[idx] + (sp ? 1.f : 0.f);
    if (sp) v = 0.f;
  }
}

// ---------------------------------------------------------------------------
// Attention (R9-verbatim): popcount QK (exact); PV accumulated in f64.
// ---------------------------------------------------------------------------
__global__ __launch_bounds__(256)
void attn_kernel_f64(const unsigned long long* __restrict__ qmask,
                     const unsigned long long* __restrict__ kmask,
                     const float* __restrict__ v, float* __restrict__ o) {
  __shared__ unsigned long long km[256];
  __shared__ float vt[256][64];
  int rb  = blockIdx.x & 3;
  int tbh = blockIdx.x >> 2;
  int h   = tbh & 7, tb = tbh >> 3;     // tb = t*16+b
  int tid = threadIdx.x;

  km[tid] = kmask[(size_t)(tb * 256 + tid) * H_ + h];
  const float* vbase = v + (size_t)tb * 256 * C_ + h * 64;
  #pragma unroll
  for (int i = 0; i < 16; ++i) {
    int f = i * 256 + tid;
    int r = f >> 4, c4 = f & 15;
    *(float4*)&vt[r][c4 * 4] = *(const float4*)(vbase + (size_t)r * C_ + c4 * 4);
  }
  int lane = tid & 63, w = tid >> 6;
  int nr = lane & 15, dg = lane >> 4;
  int n  = rb * 64 + w * 16 + nr;
  unsigned long long qm = qmask[(size_t)(tb * 256 + n) * H_ + h];
  __syncthreads();

  double acc[16];
  #pragma unroll
  for (int j = 0; j < 16; ++j) acc[j] = 0.0;

  for (int m = 0; m < 256; ++m) {
    double s = (double)__popcll(qm & km[m]) * 0.125;   // exact
    #pragma unroll
    for (int j = 0; j < 4; ++j) {
      float4 vv = *(const float4*)&vt[m][dg * 16 + j * 4];
      acc[j*4+0] = fma(s, (double)vv.x, acc[j*4+0]);
      acc[j*4+1] = fma(s, (double)vv.y, acc[j*4+1]);
      acc[j*4+2] = fma(s, (double)vv.z, acc[j*4+2]);
      acc[j*4+3] = fma(s, (double)vv.w, acc[j*4+3]);
    }
  }
  float* orow = o + (size_t)(tb * 256 + n) * C_ + h * 64 + dg * 16;
  #pragma unroll
  for (int j = 0; j < 4; ++j)
    *(float4*)(orow + j * 4) = make_float4((float)acc[j*4], (float)acc[j*4+1],
                                           (float)acc[j*4+2], (float)acc[j*4+3]);
}

// ---------------------------------------------------------------------------
extern "C" void kernel_launch(void* const* d_in, const int* in_sizes, int n_in,
                              void* d_out, int out_size, void* d_ws, size_t ws_size,
                              hipStream_t stream) {
  const float* x    = (const float*)d_in[0];
  const float* qw   = (const float*)d_in[2];
  const float* qb   = (const float*)d_in[3];
  const float* qg   = (const float*)d_in[4];
  const float* qbe  = (const float*)d_in[5];
  const float* kw   = (const float*)d_in[6];
  const float* kb   = (const float*)d_in[7];
  const float* kg   = (const float*)d_in[8];
  const float* kbe  = (const float*)d_in[9];
  const float* vw   = (const float*)d_in[10];
  const float* vb   = (const float*)d_in[11];
  const float* vg   = (const float*)d_in[12];
  const float* vbe  = (const float*)d_in[13];
  const float* pw   = (const float*)d_in[14];
  const float* pb   = (const float*)d_in[15];
  const float* pg   = (const float*)d_in[16];
  const float* pbe  = (const float*)d_in[17];
  const float* f1w  = (const float*)d_in[18];
  const float* f1b  = (const float*)d_in[19];
  const float* f1g  = (const float*)d_in[20];
  const float* f1be = (const float*)d_in[21];
  const float* f2w  = (const float*)d_in[22];
  const float* f2b  = (const float*)d_in[23];
  const float* f2g  = (const float*)d_in[24];
  const float* f2be = (const float*)d_in[25];

  char* ws = (char*)d_ws;
  float* bufY = (float*)(ws);                                   // 128 MB (16384x2048 f32)
  float* bufV = (float*)(ws + 134217728ull);                    //  32 MB
  float* bufO = (float*)(ws + 167772160ull);                    //  32 MB (o, then xo)
  unsigned long long* qmask = (unsigned long long*)(ws + 201326592ull);  // 1 MB
  unsigned long long* kmask = (unsigned long long*)(ws + 202375168ull);  // 1 MB
  float* psum = (float*)(ws + 203423744ull);                    // 4 MB (512 x 2048)
  float* psq  = (float*)(ws + 207618048ull);                    // 4 MB
  float* chp  = (float*)(ws + 211812352ull);                    // 16 KB
  double* chpd = (double*)(ws + 211828736ull);                  // 8 KB

  float* out = (float*)d_out;

  // ---- q path (bit-identical values, conflict-free 64x128) ----
  gemm_f32_t64x128<<<dim3(4,256), 256, 0, stream>>>(x, qw, qb, bufY, C_, C_);
  col_stats_partial<<<512, 256, 0, stream>>>(bufY, C_, psum, psq);
  col_stats_final<<<2, 256, 0, stream>>>(psum, psq, C_, qg, qbe, chp);
  bnlif_mask<<<8192, 256, 0, stream>>>(bufY, chp, qmask);
  // ---- k path ----
  gemm_f32_t64x128<<<dim3(4,256), 256, 0, stream>>>(x, kw, kb, bufY, C_, C_);
  col_stats_partial<<<512, 256, 0, stream>>>(bufY, C_, psum, psq);
  col_stats_final<<<2, 256, 0, stream>>>(psum, psq, C_, kg, kbe, chp);
  bnlif_mask<<<8192, 256, 0, stream>>>(bufY, chp, kmask);
  // ---- v path (f64-internal, conflict-free cols) ----
  gemm_f64_v2<<<dim3(8,256), 256, 0, stream>>>(x, vw, vb, bufY, C_, C_);
  col_stats_partial<<<512, 256, 0, stream>>>(bufY, C_, psum, psq);
  col_stats_final_f64<<<2, 256, 0, stream>>>(psum, psq, C_, vg, vbe, chpd);
  bn_apply_f64<<<2048, 256, 0, stream>>>(bufY, chpd, bufV);
  // ---- attention (R9-verbatim) ----
  attn_kernel_f64<<<2048, 256, 0, stream>>>(qmask, kmask, bufV, bufO);
  // ---- projection + residual (f64-internal, conflict-free cols) ----
  gemm_f64_v2<<<dim3(8,256), 256, 0, stream>>>(bufO, pw, pb, bufY, C_, C_);
  col_stats_partial<<<512, 256, 0, stream>>>(bufY, C_, psum, psq);
  col_stats_final_f64<<<2, 256, 0, stream>>>(psum, psq, C_, pg, pbe, chpd);
  bn_residual_f64<<<2048, 256, 0, stream>>>(bufY, chpd, x, bufO);
  // ---- MLP f1 (bit-identical values, conflict-free 128x128) ----
  gemm_f32_t128<<<dim3(16,128), 256, 0, stream>>>(bufO, f1w, f1b, bufY, HID_, C_);
  col_stats_partial<<<512, 256, 0, stream>>>(bufY, HID_, psum, psq);
  col_stats_final<<<8, 256, 0, stream>>>(psum, psq, HID_, f1g, f1be, chp);
  bnlif_inplace<<<dim3(8,4096), 256, 0, stream>>>(bufY, chp);
  // ---- MLP f2 (bit-identical values, conflict-free 64x128) ----
  gemm_f32_t64x128<<<dim3(4,256), 256, 0, stream>>>(bufY, f2w, f2b, bufV, C_, HID_);
  col_stats_partial<<<512, 256, 0, stream>>>(bufV, C_, psum, psq);
  col_stats_final<<<2, 256, 0, stream>>>(psum, psq, C_, f2g, f2be, chp);
  bnlif_final<<<dim3(2,4096), 256, 0, stream>>>(bufV, chp, bufO, out);
}

// Round 14
// 1936.739 us; speedup vs baseline: 1.0752x; 1.0235x over previous
//
#include <hip/hip_runtime.h>
#include <cstdint>

#define T_ 4
#define B_ 16
#define N_ 256
#define C_ 512
#define H_ 8
#define HID_ 2048
#define M_ (T_*B_*N_)      // 16384 rows
#define BNP_ (B_*N_)       // 4096 (b,n) pairs

// ---------------------------------------------------------------------------
// f32 GEMM, 128x128 tile, 8x8 micro, double-buffered, conflict-free fragment
// map {ty*4,64+ty*4}x{tx*4,64+tx*4}. BIT-IDENTICAL per-element math to R1.
// Used for f1 and f2.
// ---------------------------------------------------------------------------
__global__ __launch_bounds__(256, 2)
void gemm_f32_t128(const float* __restrict__ A, const float* __restrict__ W,
                   const float* __restrict__ bias, float* __restrict__ Y,
                   int Nc, int K) {
  __shared__ float As[2][16][132];
  __shared__ float Ws[2][16][132];
  const int tid  = threadIdx.x;
  const int row0 = blockIdx.y * 128;
  const int col0 = blockIdx.x * 128;
  const int tx = tid & 15, ty = tid >> 4;
  const int ar = tid >> 2;          // 0..63
  const int ac = (tid & 3) << 2;    // 0,4,8,12

  float acc[8][8];
  #pragma unroll
  for (int i = 0; i < 8; ++i)
    #pragma unroll
    for (int j = 0; j < 8; ++j) acc[i][j] = 0.f;

  const float* Ap0 = A + (size_t)(row0 + ar) * K + ac;
  const float* Ap1 = A + (size_t)(row0 + ar + 64) * K + ac;
  const float* Wp0 = W + (size_t)(col0 + ar) * K + ac;
  const float* Wp1 = W + (size_t)(col0 + ar + 64) * K + ac;

  float4 pa0 = *(const float4*)Ap0;
  float4 pa1 = *(const float4*)Ap1;
  float4 pw0 = *(const float4*)Wp0;
  float4 pw1 = *(const float4*)Wp1;
  As[0][ac+0][ar] = pa0.x; As[0][ac+1][ar] = pa0.y; As[0][ac+2][ar] = pa0.z; As[0][ac+3][ar] = pa0.w;
  As[0][ac+0][ar+64] = pa1.x; As[0][ac+1][ar+64] = pa1.y; As[0][ac+2][ar+64] = pa1.z; As[0][ac+3][ar+64] = pa1.w;
  Ws[0][ac+0][ar] = pw0.x; Ws[0][ac+1][ar] = pw0.y; Ws[0][ac+2][ar] = pw0.z; Ws[0][ac+3][ar] = pw0.w;
  Ws[0][ac+0][ar+64] = pw1.x; Ws[0][ac+1][ar+64] = pw1.y; Ws[0][ac+2][ar+64] = pw1.z; Ws[0][ac+3][ar+64] = pw1.w;
  __syncthreads();

  int buf = 0;
  for (int k0 = 0; k0 < K; k0 += 16) {
    const bool last = (k0 + 16 >= K);
    if (!last) {
      pa0 = *(const float4*)(Ap0 + k0 + 16);
      pa1 = *(const float4*)(Ap1 + k0 + 16);
      pw0 = *(const float4*)(Wp0 + k0 + 16);
      pw1 = *(const float4*)(Wp1 + k0 + 16);
    }
    #pragma unroll
    for (int kk = 0; kk < 16; ++kk) {   // ascending k — exact chain order
      float a[8], b[8];
      *(float4*)&a[0] = *(const float4*)&As[buf][kk][ty*4];
      *(float4*)&a[4] = *(const float4*)&As[buf][kk][64 + ty*4];
      *(float4*)&b[0] = *(const float4*)&Ws[buf][kk][tx*4];
      *(float4*)&b[4] = *(const float4*)&Ws[buf][kk][64 + tx*4];
      #pragma unroll
      for (int i = 0; i < 8; ++i)
        #pragma unroll
        for (int j = 0; j < 8; ++j)
          acc[i][j] = fmaf(a[i], b[j], acc[i][j]);
    }
    if (!last) {
      int nb = buf ^ 1;
      As[nb][ac+0][ar] = pa0.x; As[nb][ac+1][ar] = pa0.y; As[nb][ac+2][ar] = pa0.z; As[nb][ac+3][ar] = pa0.w;
      As[nb][ac+0][ar+64] = pa1.x; As[nb][ac+1][ar+64] = pa1.y; As[nb][ac+2][ar+64] = pa1.z; As[nb][ac+3][ar+64] = pa1.w;
      Ws[nb][ac+0][ar] = pw0.x; Ws[nb][ac+1][ar] = pw0.y; Ws[nb][ac+2][ar] = pw0.z; Ws[nb][ac+3][ar] = pw0.w;
      Ws[nb][ac+0][ar+64] = pw1.x; Ws[nb][ac+1][ar+64] = pw1.y; Ws[nb][ac+2][ar+64] = pw1.z; Ws[nb][ac+3][ar+64] = pw1.w;
      __syncthreads();
      buf = nb;
    }
  }

  #pragma unroll
  for (int ih = 0; ih < 2; ++ih)
    #pragma unroll
    for (int i = 0; i < 4; ++i) {
      size_t r = (size_t)(row0 + ih*64 + ty*4 + i);
      #pragma unroll
      for (int jh = 0; jh < 2; ++jh) {
        int c = col0 + jh*64 + tx*4;
        float4 o4;
        o4.x = acc[ih*4+i][jh*4+0] + bias[c+0];
        o4.y = acc[ih*4+i][jh*4+1] + bias[c+1];
        o4.z = acc[ih*4+i][jh*4+2] + bias[c+2];
        o4.w = acc[ih*4+i][jh*4+3] + bias[c+3];
        *(float4*)(Y + r * Nc + c) = o4;
      }
    }
}

// ---------------------------------------------------------------------------
// Fused q+k GEMM: 64-row tile x (128 q-cols || 128 k-cols), shared A staging.
// Per-element chain identical to separate GEMMs (independent accumulators,
// ascending k, plain +bias) -> bit-identical q and k outputs.
// Grid (C_/128, M_/64) = (4, 256).
// ---------------------------------------------------------------------------
__global__ __launch_bounds__(256, 2)
void gemm_f32_qk(const float* __restrict__ A,
                 const float* __restrict__ Wq, const float* __restrict__ bq,
                 const float* __restrict__ Wk, const float* __restrict__ bk,
                 float* __restrict__ Yq, float* __restrict__ Yk,
                 int Nc, int K) {
  __shared__ float As[2][16][68];
  __shared__ float Wqs[2][16][132];
  __shared__ float Wks[2][16][132];
  const int tid  = threadIdx.x;
  const int row0 = blockIdx.y * 64;
  const int col0 = blockIdx.x * 128;
  const int tx = tid & 15, ty = tid >> 4;
  const int ar = tid >> 2;          // 0..63
  const int ac = (tid & 3) << 2;    // 0,4,8,12

  float accq[4][8], acck[4][8];
  #pragma unroll
  for (int i = 0; i < 4; ++i)
    #pragma unroll
    for (int j = 0; j < 8; ++j) { accq[i][j] = 0.f; acck[i][j] = 0.f; }

  const float* Ap   = A  + (size_t)(row0 + ar) * K + ac;
  const float* Wqp0 = Wq + (size_t)(col0 + ar) * K + ac;
  const float* Wqp1 = Wq + (size_t)(col0 + ar + 64) * K + ac;
  const float* Wkp0 = Wk + (size_t)(col0 + ar) * K + ac;
  const float* Wkp1 = Wk + (size_t)(col0 + ar + 64) * K + ac;

  float4 pa  = *(const float4*)Ap;
  float4 pq0 = *(const float4*)Wqp0;
  float4 pq1 = *(const float4*)Wqp1;
  float4 pk0 = *(const float4*)Wkp0;
  float4 pk1 = *(const float4*)Wkp1;
  As[0][ac+0][ar] = pa.x; As[0][ac+1][ar] = pa.y; As[0][ac+2][ar] = pa.z; As[0][ac+3][ar] = pa.w;
  Wqs[0][ac+0][ar] = pq0.x; Wqs[0][ac+1][ar] = pq0.y; Wqs[0][ac+2][ar] = pq0.z; Wqs[0][ac+3][ar] = pq0.w;
  Wqs[0][ac+0][ar+64] = pq1.x; Wqs[0][ac+1][ar+64] = pq1.y; Wqs[0][ac+2][ar+64] = pq1.z; Wqs[0][ac+3][ar+64] = pq1.w;
  Wks[0][ac+0][ar] = pk0.x; Wks[0][ac+1][ar] = pk0.y; Wks[0][ac+2][ar] = pk0.z; Wks[0][ac+3][ar] = pk0.w;
  Wks[0][ac+0][ar+64] = pk1.x; Wks[0][ac+1][ar+64] = pk1.y; Wks[0][ac+2][ar+64] = pk1.z; Wks[0][ac+3][ar+64] = pk1.w;
  __syncthreads();

  int buf = 0;
  for (int k0 = 0; k0 < K; k0 += 16) {
    const bool last = (k0 + 16 >= K);
    if (!last) {
      pa  = *(const float4*)(Ap   + k0 + 16);
      pq0 = *(const float4*)(Wqp0 + k0 + 16);
      pq1 = *(const float4*)(Wqp1 + k0 + 16);
      pk0 = *(const float4*)(Wkp0 + k0 + 16);
      pk1 = *(const float4*)(Wkp1 + k0 + 16);
    }
    #pragma unroll
    for (int kk = 0; kk < 16; ++kk) {   // ascending k — exact chain order
      float4 av = *(const float4*)&As[buf][kk][ty*4];
      float a[4] = {av.x, av.y, av.z, av.w};
      float b[8];
      *(float4*)&b[0] = *(const float4*)&Wqs[buf][kk][tx*4];
      *(float4*)&b[4] = *(const float4*)&Wqs[buf][kk][64 + tx*4];
      #pragma unroll
      for (int i = 0; i < 4; ++i)
        #pragma unroll
        for (int j = 0; j < 8; ++j)
          accq[i][j] = fmaf(a[i], b[j], accq[i][j]);
      *(float4*)&b[0] = *(const float4*)&Wks[buf][kk][tx*4];
      *(float4*)&b[4] = *(const float4*)&Wks[buf][kk][64 + tx*4];
      #pragma unroll
      for (int i = 0; i < 4; ++i)
        #pragma unroll
        for (int j = 0; j < 8; ++j)
          acck[i][j] = fmaf(a[i], b[j], acck[i][j]);
    }
    if (!last) {
      int nb = buf ^ 1;
      As[nb][ac+0][ar] = pa.x; As[nb][ac+1][ar] = pa.y; As[nb][ac+2][ar] = pa.z; As[nb][ac+3][ar] = pa.w;
      Wqs[nb][ac+0][ar] = pq0.x; Wqs[nb][ac+1][ar] = pq0.y; Wqs[nb][ac+2][ar] = pq0.z; Wqs[nb][ac+3][ar] = pq0.w;
      Wqs[nb][ac+0][ar+64] = pq1.x; Wqs[nb][ac+1][ar+64] = pq1.y; Wqs[nb][ac+2][ar+64] = pq1.z; Wqs[nb][ac+3][ar+64] = pq1.w;
      Wks[nb][ac+0][ar] = pk0.x; Wks[nb][ac+1][ar] = pk0.y; Wks[nb][ac+2][ar] = pk0.z; Wks[nb][ac+3][ar] = pk0.w;
      Wks[nb][ac+0][ar+64] = pk1.x; Wks[nb][ac+1][ar+64] = pk1.y; Wks[nb][ac+2][ar+64] = pk1.z; Wks[nb][ac+3][ar+64] = pk1.w;
      __syncthreads();
      buf = nb;
    }
  }

  #pragma unroll
  for (int i = 0; i < 4; ++i) {
    size_t r = (size_t)(row0 + ty*4 + i);
    #pragma unroll
    for (int jh = 0; jh < 2; ++jh) {
      int c = col0 + jh*64 + tx*4;
      float4 oq, ok;
      oq.x = accq[i][jh*4+0] + bq[c+0];
      oq.y = accq[i][jh*4+1] + bq[c+1];
      oq.z = accq[i][jh*4+2] + bq[c+2];
      oq.w = accq[i][jh*4+3] + bq[c+3];
      *(float4*)(Yq + r * Nc + c) = oq;
      ok.x = acck[i][jh*4+0] + bk[c+0];
      ok.y = acck[i][jh*4+1] + bk[c+1];
      ok.z = acck[i][jh*4+2] + bk[c+2];
      ok.w = acck[i][jh*4+3] + bk[c+3];
      *(float4*)(Yk + r * Nc + c) = ok;
    }
  }
}

// ---------------------------------------------------------------------------
// v/p path GEMM v3: f32 in/out, f64 accumulation; 64x128 tile, 4x8 micro,
// pre-converted f64 LDS, double-buffered. Per-element chain IDENTICAL to R9
// (ascending-k single-acc f64 fma + f64 bias) -> bit-identical outputs.
// Cols per thread {tx*2, 32+tx*2, 64+tx*2, 96+tx*2}. Grid (Nc/128, M/64).
// ---------------------------------------------------------------------------
__global__ __launch_bounds__(256, 2)
void gemm_f64_v3(const float* __restrict__ A, const float* __restrict__ W,
                 const float* __restrict__ bias, float* __restrict__ Y,
                 int Nc, int K) {
  __shared__ double As[2][16][68];
  __shared__ double Ws[2][16][132];
  const int tid  = threadIdx.x;
  const int row0 = blockIdx.y * 64;
  const int col0 = blockIdx.x * 128;
  const int tx = tid & 15, ty = tid >> 4;
  const int lr = tid >> 2;          // 0..63
  const int lk = (tid & 3) << 2;    // 0,4,8,12

  double acc[4][8];                 // [row][colgroup*2 + e]
  #pragma unroll
  for (int i = 0; i < 4; ++i)
    #pragma unroll
    for (int j = 0; j < 8; ++j) acc[i][j] = 0.0;

  const float* Ap  = A + (size_t)(row0 + lr) * K + lk;
  const float* Wp0 = W + (size_t)(col0 + lr) * K + lk;
  const float* Wp1 = W + (size_t)(col0 + lr + 64) * K + lk;

  float4 pa  = *(const float4*)Ap;
  float4 pw0 = *(const float4*)Wp0;
  float4 pw1 = *(const float4*)Wp1;
  As[0][lk+0][lr] = (double)pa.x; As[0][lk+1][lr] = (double)pa.y;
  As[0][lk+2][lr] = (double)pa.z; As[0][lk+3][lr] = (double)pa.w;
  Ws[0][lk+0][lr] = (double)pw0.x; Ws[0][lk+1][lr] = (double)pw0.y;
  Ws[0][lk+2][lr] = (double)pw0.z; Ws[0][lk+3][lr] = (double)pw0.w;
  Ws[0][lk+0][lr+64] = (double)pw1.x; Ws[0][lk+1][lr+64] = (double)pw1.y;
  Ws[0][lk+2][lr+64] = (double)pw1.z; Ws[0][lk+3][lr+64] = (double)pw1.w;
  __syncthreads();

  int buf = 0;
  for (int k0 = 0; k0 < K; k0 += 16) {
    const bool last = (k0 + 16 >= K);
    if (!last) {
      pa  = *(const float4*)(Ap  + k0 + 16);
      pw0 = *(const float4*)(Wp0 + k0 + 16);
      pw1 = *(const float4*)(Wp1 + k0 + 16);
    }
    #pragma unroll
    for (int kk = 0; kk < 16; ++kk) {   // ascending k — exact chain order
      double a[4], b[8];
      *(double2*)&a[0] = *(const double2*)&As[buf][kk][ty*4];
      *(double2*)&a[2] = *(const double2*)&As[buf][kk][ty*4+2];
      *(double2*)&b[0] = *(const double2*)&Ws[buf][kk][tx*2];
      *(double2*)&b[2] = *(const double2*)&Ws[buf][kk][32 + tx*2];
      *(double2*)&b[4] = *(const double2*)&Ws[buf][kk][64 + tx*2];
      *(double2*)&b[6] = *(const double2*)&Ws[buf][kk][96 + tx*2];
      #pragma unroll
      for (int i = 0; i < 4; ++i)
        #pragma unroll
        for (int j = 0; j < 8; ++j)
          acc[i][j] = fma(a[i], b[j], acc[i][j]);
    }
    if (!last) {
      int nb = buf ^ 1;
      As[nb][lk+0][lr] = (double)pa.x; As[nb][lk+1][lr] = (double)pa.y;
      As[nb][lk+2][lr] = (double)pa.z; As[nb][lk+3][lr] = (double)pa.w;
      Ws[nb][lk+0][lr] = (double)pw0.x; Ws[nb][lk+1][lr] = (double)pw0.y;
      Ws[nb][lk+2][lr] = (double)pw0.z; Ws[nb][lk+3][lr] = (double)pw0.w;
      Ws[nb][lk+0][lr+64] = (double)pw1.x; Ws[nb][lk+1][lr+64] = (double)pw1.y;
      Ws[nb][lk+2][lr+64] = (double)pw1.z; Ws[nb][lk+3][lr+64] = (double)pw1.w;
      __syncthreads();
      buf = nb;
    }
  }

  #pragma unroll
  for (int i = 0; i < 4; ++i) {
    size_t r = (size_t)(row0 + ty*4 + i);
    #pragma unroll
    for (int g = 0; g < 4; ++g) {
      int c = col0 + g*32 + tx*2;
      float2 o2;
      o2.x = (float)(acc[i][g*2+0] + (double)bias[c+0]);
      o2.y = (float)(acc[i][g*2+1] + (double)bias[c+1]);
      *(float2*)(Y + r * Nc + c) = o2;
    }
  }
}

// ---------------------------------------------------------------------------
// BN stats stage 1 (R1-verbatim)
// ---------------------------------------------------------------------------
__global__ __launch_bounds__(256)
void col_stats_partial(const float* __restrict__ Y, int Nc,
                       float* __restrict__ psum, float* __restrict__ psq) {
  const int r0 = blockIdx.x * 32;
  for (int c = threadIdx.x; c < Nc; c += 256) {
    float s = 0.f, q = 0.f;
    const float* p = Y + (size_t)r0 * Nc + c;
    for (int r = 0; r < 32; ++r) {
      float v = p[(size_t)r * Nc];
      s += v;
      q = fmaf(v, v, q);
    }
    psum[(size_t)blockIdx.x * Nc + c] = s;
    psq [(size_t)blockIdx.x * Nc + c] = q;
  }
}

// stage 2 (R1-verbatim): f32 chp for q/k/f1/f2 paths
__global__ void col_stats_final(const float* __restrict__ psum, const float* __restrict__ psq,
                                int Nc, const float* __restrict__ g, const float* __restrict__ beta,
                                float* __restrict__ chp) {
  int c = blockIdx.x * blockDim.x + threadIdx.x;
  if (c >= Nc) return;
  double s = 0.0, q = 0.0;
  for (int p = 0; p < 512; ++p) {
    s += (double)psum[(size_t)p * Nc + c];
    q += (double)psq [(size_t)p * Nc + c];
  }
  double mean = s / (double)M_;
  double var  = q / (double)M_ - mean * mean;
  float alpha = g[c] / sqrtf((float)var + 1e-5f);
  chp[2*c]   = alpha;
  chp[2*c+1] = fmaf(-(float)mean, alpha, beta[c]);   // beta - mean*alpha
}

// stage 2 for v/p paths: f64 affine params (R9-verbatim)
__global__ void col_stats_final_f64(const float* __restrict__ psum, const float* __restrict__ psq,
                                    int Nc, const float* __restrict__ g, const float* __restrict__ beta,
                                    double* __restrict__ chpd) {
  int c = blockIdx.x * blockDim.x + threadIdx.x;
  if (c >= Nc) return;
  double s = 0.0, q = 0.0;
  for (int p = 0; p < 512; ++p) {
    s += (double)psum[(size_t)p * Nc + c];
    q += (double)psq [(size_t)p * Nc + c];
  }
  double mean = s / (double)M_;
  double var  = q / (double)M_ - mean * mean;
  double alpha = (double)g[c] / sqrt(var + 1e-5);
  chpd[2*c]   = alpha;
  chpd[2*c+1] = (double)beta[c] - mean * alpha;
}

// ---------------------------------------------------------------------------
// BN + LIF masks (R1-verbatim) — q/k decisions, frozen
// ---------------------------------------------------------------------------
__global__ __launch_bounds__(256)
void bnlif_mask(const float* __restrict__ Y, const float* __restrict__ chp,
                unsigned long long* __restrict__ mask) {
  int lane = threadIdx.x & 63;
  int u  = blockIdx.x * 4 + (threadIdx.x >> 6);
  int bn = u >> 3, cg = u & 7;          // cg == head (Dh==64)
  int c  = cg * 64 + lane;
  float alpha = chp[2*c], bb = chp[2*c+1];
  float v = 0.f;
  #pragma unroll
  for (int t = 0; t < 4; ++t) {
    float y  = Y[((size_t)(t * BNP_ + bn)) * C_ + c];
    float uu = fmaf(y, alpha, bb);
    v = v + (uu - v) * 0.5f;            // v += (x - v)/tau, tau=2
    bool sp = (v >= 1.0f);
    unsigned long long m = __ballot(sp);
    if (sp) v = 0.f;                    // hard reset
    if (lane == 0) mask[((size_t)(t * BNP_ + bn)) * H_ + cg] = m;
  }
}

// BN apply (v path), f64 math → f32 out (R9-verbatim)
__global__ void bn_apply_f64(const float* __restrict__ Y, const double* __restrict__ chpd,
                             float* __restrict__ out) {
  const long total4 = (long)M_ * C_ / 4;
  for (long i = (long)blockIdx.x * blockDim.x + threadIdx.x; i < total4;
       i += (long)gridDim.x * blockDim.x) {
    int c4 = (int)(i & (C_/4 - 1)) * 4;
    float4 y = ((const float4*)Y)[i];
    float4 r;
    r.x = (float)fma((double)y.x, chpd[2*(c4+0)], chpd[2*(c4+0)+1]);
    r.y = (float)fma((double)y.y, chpd[2*(c4+1)], chpd[2*(c4+1)+1]);
    r.z = (float)fma((double)y.z, chpd[2*(c4+2)], chpd[2*(c4+2)+1]);
    r.w = (float)fma((double)y.w, chpd[2*(c4+3)], chpd[2*(c4+3)+1]);
    ((float4*)out)[i] = r;
  }
}

// xo = x + BN(Yp), f64 math → f32 out (R9-verbatim)
__global__ void bn_residual_f64(const float* __restrict__ Y, const double* __restrict__ chpd,
                                const float* __restrict__ x, float* __restrict__ out) {
  const long total4 = (long)M_ * C_ / 4;
  for (long i = (long)blockIdx.x * blockDim.x + threadIdx.x; i < total4;
       i += (long)gridDim.x * blockDim.x) {
    int c4 = (int)(i & (C_/4 - 1)) * 4;
    float4 y = ((const float4*)Y)[i];
    float4 xv = ((const float4*)x)[i];
    float4 r;
    r.x = (float)((double)xv.x + fma((double)y.x, chpd[2*(c4+0)], chpd[2*(c4+0)+1]));
    r.y = (float)((double)xv.y + fma((double)y.y, chpd[2*(c4+1)], chpd[2*(c4+1)+1]));
    r.z = (float)((double)xv.z + fma((double)y.z, chpd[2*(c4+2)], chpd[2*(c4+2)+1]));
    r.w = (float)((double)xv.w + fma((double)y.w, chpd[2*(c4+3)], chpd[2*(c4+3)+1]));
    ((float4*)out)[i] = r;
  }
}

// BN + LIF for f1 (R1-verbatim), spikes in place as 1.0f/0.0f
__global__ __launch_bounds__(256)
void bnlif_inplace(float* __restrict__ Y, const float* __restrict__ chp) {
  int c  = blockIdx.x * 256 + threadIdx.x;   // < 2048
  int bn = blockIdx.y;
  float alpha = chp[2*c], bb = chp[2*c+1];
  float v = 0.f;
  #pragma unroll
  for (int t = 0; t < 4; ++t) {
    size_t idx = ((size_t)(t * BNP_ + bn)) * HID_ + c;
    float uu = fmaf(Y[idx], alpha, bb);
    v = v + (uu - v) * 0.5f;
    bool sp = (v >= 1.f);
    Y[idx] = sp ? 1.f : 0.f;
    if (sp) v = 0.f;
  }
}

// BN + LIF for f2 + final residual (R1-verbatim)
__global__ __launch_bounds__(256)
void bnlif_final(const float* __restrict__ Y, const float* __restrict__ chp,
                 const float* __restrict__ xo, float* __restrict__ out) {
  int c  = blockIdx.x * 256 + threadIdx.x;   // < 512
  int bn = blockIdx.y;
  float alpha = chp[2*c], bb = chp[2*c+1];
  float v = 0.f;
  #pragma unroll
  for (int t = 0; t < 4; ++t) {
    size_t idx = ((size_t)(t * BNP_ + bn)) * C_ + c;
    float uu = fmaf(Y[idx], alpha, bb);
    v = v + (uu - v) * 0.5f;
    bool sp = (v >= 1.f);
    out[idx] = xo[idx] + (sp ? 1.f : 0.f);
    if (sp) v = 0.f;
  }
}

// ---------------------------------------------------------------------------
// Attention (R9-verbatim): popcount QK (exact); PV accumulated in f64.
// ---------------------------------------------------------------------------
__global__ __launch_bounds__(256)
void attn_kernel_f64(const unsigned long long* __restrict__ qmask,
                     const unsigned long long* __restrict__ kmask,
                     const float* __restrict__ v, float* __restrict__ o) {
  __shared__ unsigned long long km[256];
  __shared__ float vt[256][64];
  int rb  = blockIdx.x & 3;
  int tbh = blockIdx.x >> 2;
  int h   = tbh & 7, tb = tbh >> 3;     // tb = t*16+b
  int tid = threadIdx.x;

  km[tid] = kmask[(size_t)(tb * 256 + tid) * H_ + h];
  const float* vbase = v + (size_t)tb * 256 * C_ + h * 64;
  #pragma unroll
  for (int i = 0; i < 16; ++i) {
    int f = i * 256 + tid;
    int r = f >> 4, c4 = f & 15;
    *(float4*)&vt[r][c4 * 4] = *(const float4*)(vbase + (size_t)r * C_ + c4 * 4);
  }
  int lane = tid & 63, w = tid >> 6;
  int nr = lane & 15, dg = lane >> 4;
  int n  = rb * 64 + w * 16 + nr;
  unsigned long long qm = qmask[(size_t)(tb * 256 + n) * H_ + h];
  __syncthreads();

  double acc[16];
  #pragma unroll
  for (int j = 0; j < 16; ++j) acc[j] = 0.0;

  for (int m = 0; m < 256; ++m) {
    double s = (double)__popcll(qm & km[m]) * 0.125;   // exact
    #pragma unroll
    for (int j = 0; j < 4; ++j) {
      float4 vv = *(const float4*)&vt[m][dg * 16 + j * 4];
      acc[j*4+0] = fma(s, (double)vv.x, acc[j*4+0]);
      acc[j*4+1] = fma(s, (double)vv.y, acc[j*4+1]);
      acc[j*4+2] = fma(s, (double)vv.z, acc[j*4+2]);
      acc[j*4+3] = fma(s, (double)vv.w, acc[j*4+3]);
    }
  }
  float* orow = o + (size_t)(tb * 256 + n) * C_ + h * 64 + dg * 16;
  #pragma unroll
  for (int j = 0; j < 4; ++j)
    *(float4*)(orow + j * 4) = make_float4((float)acc[j*4], (float)acc[j*4+1],
                                           (float)acc[j*4+2], (float)acc[j*4+3]);
}

// ---------------------------------------------------------------------------
extern "C" void kernel_launch(void* const* d_in, const int* in_sizes, int n_in,
                              void* d_out, int out_size, void* d_ws, size_t ws_size,
                              hipStream_t stream) {
  const float* x    = (const float*)d_in[0];
  const float* qw   = (const float*)d_in[2];
  const float* qb   = (const float*)d_in[3];
  const float* qg   = (const float*)d_in[4];
  const float* qbe  = (const float*)d_in[5];
  const float* kw   = (const float*)d_in[6];
  const float* kb   = (const float*)d_in[7];
  const float* kg   = (const float*)d_in[8];
  const float* kbe  = (const float*)d_in[9];
  const float* vw   = (const float*)d_in[10];
  const float* vb   = (const float*)d_in[11];
  const float* vg   = (const float*)d_in[12];
  const float* vbe  = (const float*)d_in[13];
  const float* pw   = (const float*)d_in[14];
  const float* pb   = (const float*)d_in[15];
  const float* pg   = (const float*)d_in[16];
  const float* pbe  = (const float*)d_in[17];
  const float* f1w  = (const float*)d_in[18];
  const float* f1b  = (const float*)d_in[19];
  const float* f1g  = (const float*)d_in[20];
  const float* f1be = (const float*)d_in[21];
  const float* f2w  = (const float*)d_in[22];
  const float* f2b  = (const float*)d_in[23];
  const float* f2g  = (const float*)d_in[24];
  const float* f2be = (const float*)d_in[25];

  char* ws = (char*)d_ws;
  float* bufY = (float*)(ws);                                   // 128 MB (16384x2048 f32)
  float* bufK = bufY + 8388608;                                 // k parks at bufY+32MB
  float* bufV = (float*)(ws + 134217728ull);                    //  32 MB
  float* bufO = (float*)(ws + 167772160ull);                    //  32 MB (o, then xo)
  unsigned long long* qmask = (unsigned long long*)(ws + 201326592ull);  // 1 MB
  unsigned long long* kmask = (unsigned long long*)(ws + 202375168ull);  // 1 MB
  float* psum = (float*)(ws + 203423744ull);                    // 4 MB (512 x 2048)
  float* psq  = (float*)(ws + 207618048ull);                    // 4 MB
  float* chp  = (float*)(ws + 211812352ull);                    // 16 KB
  double* chpd = (double*)(ws + 211828736ull);                  // 8 KB

  float* out = (float*)d_out;

  // ---- fused q+k GEMM (bit-identical values, shared A staging) ----
  gemm_f32_qk<<<dim3(4,256), 256, 0, stream>>>(x, qw, qb, kw, kb, bufY, bufK, C_, C_);
  // q stats + mask
  col_stats_partial<<<512, 256, 0, stream>>>(bufY, C_, psum, psq);
  col_stats_final<<<2, 256, 0, stream>>>(psum, psq, C_, qg, qbe, chp);
  bnlif_mask<<<8192, 256, 0, stream>>>(bufY, chp, qmask);
  // k stats + mask
  col_stats_partial<<<512, 256, 0, stream>>>(bufK, C_, psum, psq);
  col_stats_final<<<2, 256, 0, stream>>>(psum, psq, C_, kg, kbe, chp);
  bnlif_mask<<<8192, 256, 0, stream>>>(bufK, chp, kmask);
  // ---- v path (f64-internal, 64x128 4x8 retile — bit-identical chain) ----
  gemm_f64_v3<<<dim3(4,256), 256, 0, stream>>>(x, vw, vb, bufY, C_, C_);
  col_stats_partial<<<512, 256, 0, stream>>>(bufY, C_, psum, psq);
  col_stats_final_f64<<<2, 256, 0, stream>>>(psum, psq, C_, vg, vbe, chpd);
  bn_apply_f64<<<2048, 256, 0, stream>>>(bufY, chpd, bufV);
  // ---- attention (R9-verbatim) ----
  attn_kernel_f64<<<2048, 256, 0, stream>>>(qmask, kmask, bufV, bufO);
  // ---- projection + residual (f64-internal retile) ----
  gemm_f64_v3<<<dim3(4,256), 256, 0, stream>>>(bufO, pw, pb, bufY, C_, C_);
  col_stats_partial<<<512, 256, 0, stream>>>(bufY, C_, psum, psq);
  col_stats_final_f64<<<2, 256, 0, stream>>>(psum, psq, C_, pg, pbe, chpd);
  bn_residual_f64<<<2048, 256, 0, stream>>>(bufY, chpd, x, bufO);
  // ---- MLP f1 (bit-identical values, conflict-free 128x128) ----
  gemm_f32_t128<<<dim3(16,128), 256, 0, stream>>>(bufO, f1w, f1b, bufY, HID_, C_);
  col_stats_partial<<<512, 256, 0, stream>>>(bufY, HID_, psum, psq);
  col_stats_final<<<8, 256, 0, stream>>>(psum, psq, HID_, f1g, f1be, chp);
  bnlif_inplace<<<dim3(8,4096), 256, 0, stream>>>(bufY, chp);
  // ---- MLP f2 (bit-identical values, 128x128 tile) ----
  gemm_f32_t128<<<dim3(4,128), 256, 0, stream>>>(bufY, f2w, f2b, bufV, C_, HID_);
  col_stats_partial<<<512, 256, 0, stream>>>(bufV, C_, psum, psq);
  col_stats_final<<<2, 256, 0, stream>>>(psum, psq, C_, f2g, f2be, chp);
  bnlif_final<<<dim3(2,4096), 256, 0, stream>>>(bufV, chp, bufO, out);
}